// Round 10
// baseline (2081.011 us; speedup 1.0000x reference)
//
#include <hip/hip_runtime.h>
#include <hip/hip_bf16.h>

#define T_STEPS 4
#define N 4096
#define E 65536
#define XD 256
#define HD 256
#define ZD 64

typedef __hip_bfloat16 bf16;
typedef __attribute__((ext_vector_type(8))) short short8;
typedef __attribute__((ext_vector_type(4))) float f32x4;

__device__ __forceinline__ float b2f(bf16 v){ return __bfloat162float(v); }
__device__ __forceinline__ bf16 f2b(float v){ return __float2bfloat16(v); }
__device__ __forceinline__ short f2s(float v){ return __builtin_bit_cast(short, f2b(v)); }
__device__ __forceinline__ float bits2f(unsigned int s){ return __builtin_bit_cast(float, s << 16); }
__device__ __forceinline__ float s2f(short s){ return bits2f((unsigned int)(unsigned short)s); }
__device__ __forceinline__ float splus(float x){ return (x > 20.f) ? x : log1pf(expf(x)); }
__device__ __forceinline__ float sigm(float x){ return 1.f/(1.f + expf(-x)); }

__device__ __forceinline__ float ldI(const void* p, size_t i, int f){
  return f ? ((const float*)p)[i] : b2f(((const bf16*)p)[i]);
}
__device__ __forceinline__ void stO(void* p, size_t i, float v, int f){
  if (f) ((float*)p)[i] = v; else ((bf16*)p)[i] = f2b(v);
}
__device__ __forceinline__ void ld8b(const bf16* p, float v[8]){
  uint4 u = *(const uint4*)p;
  v[0]=bits2f(u.x & 0xffffu); v[1]=bits2f(u.x >> 16);
  v[2]=bits2f(u.y & 0xffffu); v[3]=bits2f(u.y >> 16);
  v[4]=bits2f(u.z & 0xffffu); v[5]=bits2f(u.z >> 16);
  v[6]=bits2f(u.w & 0xffffu); v[7]=bits2f(u.w >> 16);
}
// 8 weight cols (dtype-dispatched)
__device__ __forceinline__ void ldW8(const void* W, size_t off, int f, float w[8]){
  if (f == 0){ ld8b((const bf16*)W + off, w); }
  else {
    const float* Wf = (const float*)W + off;
    float4 a = *(const float4*)Wf, b = *(const float4*)(Wf + 4);
    w[0]=a.x; w[1]=a.y; w[2]=a.z; w[3]=a.w; w[4]=b.x; w[5]=b.y; w[6]=b.z; w[7]=b.w;
  }
}
__device__ __forceinline__ unsigned int pack2(float a, float b){
  return (unsigned int)(unsigned short)__builtin_bit_cast(unsigned short, f2b(a))
       | ((unsigned int)(unsigned short)__builtin_bit_cast(unsigned short, f2b(b)) << 16);
}

union SMem {
  struct { short As[64*40]; short Wt[64*40]; } g;                        // 10.2 KB (GEMM)
  struct { short Zi[64*72]; short Zj[64*72]; short Adj[64*72]; float red[256]; } z; // 28.7 KB
  int sh[256];
  float red[256];
};

struct KP {
  const void *x, *adj, *eps, *h0;
  const int* ei;
  const void *phi_x_w, *phi_x_b, *phi_z_w, *phi_z_b;
  const void *enc_w, *enc_b, *enc_mean_w, *enc_mean_b, *enc_std_w, *enc_std_b;
  const void *prior_w, *prior_b, *prior_mean_w, *prior_mean_b, *prior_std_w, *prior_std_b;
  const void *gxz, *ghz, *gxr, *ghr, *gxh, *ghh;
  void* out;
  float* scal; int* dflag; float* dinv; int* offs; int* srcs; float* enorm; int* deg;
  float* h_prev; bf16* h_bf; bf16* phiXa; bf16* Tb1; bf16* Tb2;
  bf16* zbf; float* z_g; bf16* Gs1; bf16* Gsx; bf16* Gh2;
};

#define OUT_EM ((size_t)2)
#define OUT_PM ((size_t)(2 + (size_t)T_STEPS*N*ZD))
#define OUT_H  ((size_t)(2 + (size_t)2*T_STEPS*N*ZD))

// ---------------- MFMA 64x64 tile: C = [A1|A2] @ W(+bias)(+relu), bf16 out ----------------
__device__ void mfma_tile(SMem& sm, int tid, int f,
    const void* A1, int am1, int lda1, const void* A2, int am2, int lda2,
    int K1, int K, const void* W, int ldw, int wcol,
    const void* bias, int act, bf16* C, int ldc, int row0, int ccol0){
  int ar = tid >> 2, akk = (tid & 3)*8;
  int wk = tid >> 3, wn = (tid & 7)*8;
  int wave = tid >> 6, lane = tid & 63, m = lane & 15, kq = lane >> 4;
  f32x4 acc[4] = {};
  for (int k0 = 0; k0 < K; k0 += 32){
    const void* A; int am, lda, kb;
    if (k0 < K1){ A = A1; am = am1; lda = lda1; kb = k0; }
    else        { A = A2; am = am2; lda = lda2; kb = k0 - K1; }
    size_t aidx = (size_t)(row0 + ar)*lda + kb + akk;
    short8 av;
    if (am == 2 || (am == 1 && f == 0)){
      av = *(const short8*)((const short*)A + aidx);
    } else {
      const float* Af = (const float*)A;
      float4 u0 = *(const float4*)(Af + aidx);
      float4 u1 = *(const float4*)(Af + aidx + 4);
      av[0]=f2s(u0.x); av[1]=f2s(u0.y); av[2]=f2s(u0.z); av[3]=f2s(u0.w);
      av[4]=f2s(u1.x); av[5]=f2s(u1.y); av[6]=f2s(u1.z); av[7]=f2s(u1.w);
    }
    *(short8*)&sm.g.As[ar*40 + akk] = av;
    size_t wi = (size_t)(k0 + wk)*ldw + wcol + wn;
    float wf[8]; short wv[8];
    if (f == 0){
      short8 t8 = *(const short8*)((const short*)W + wi);
      #pragma unroll
      for (int j = 0; j < 8; j++) wv[j] = t8[j];
    } else {
      ldW8(W, wi, f, wf);
      #pragma unroll
      for (int j = 0; j < 8; j++) wv[j] = f2s(wf[j]);
    }
    #pragma unroll
    for (int j = 0; j < 8; j++){
      int nrow = wn + j;
      int col = (((wk >> 3) ^ ((nrow >> 3) & 3)) << 3) | (wk & 7);
      sm.g.Wt[nrow*40 + col] = wv[j];
    }
    __syncthreads();
    short8 afr = *(const short8*)&sm.g.As[(wave*16 + m)*40 + kq*8];
    #pragma unroll
    for (int t4 = 0; t4 < 4; t4++){
      int nb = t4*16 + m;
      short8 bfr = *(const short8*)&sm.g.Wt[nb*40 + ((kq ^ ((nb >> 3) & 3)) << 3)];
      acc[t4] = __builtin_amdgcn_mfma_f32_16x16x32_bf16(afr, bfr, acc[t4], 0, 0, 0);
    }
    __syncthreads();
  }
  #pragma unroll
  for (int t4 = 0; t4 < 4; t4++){
    int c = ccol0 + t4*16 + m;
    float bv = bias ? ldI(bias, wcol + t4*16 + m, f) : 0.f;
    #pragma unroll
    for (int reg = 0; reg < 4; reg++){
      int r = row0 + wave*16 + kq*4 + reg;
      float v = acc[t4][reg] + bv;
      if (act == 1) v = fmaxf(v, 0.f);
      C[(size_t)r*ldc + c] = f2b(v);
    }
  }
}

// ---------------- dec 64x64 tile via MFMA, adj through LDS ----------------
__device__ void dec_tile1(const KP& p, SMem& sm, int tid, int t, int u, int f){
  int i0 = (u >> 6)*64, j0 = (u & 63)*64;
  size_t aoff = (size_t)t*N*N;
  #pragma unroll
  for (int i = 0; i < 2; i++){
    int idx = tid + i*256;
    int r = idx >> 3, c = idx & 7;
    int col = ((c ^ ((r >> 3) & 3)) << 3);
    *(short8*)&sm.z.Zi[r*72 + col] = *(const short8*)((const short*)p.zbf + (size_t)(i0+r)*ZD + c*8);
    *(short8*)&sm.z.Zj[r*72 + col] = *(const short8*)((const short*)p.zbf + (size_t)(j0+r)*ZD + c*8);
  }
  {
    int row = tid >> 2, c0 = (tid & 3)*16;
    if (f){
      const float* ap = (const float*)p.adj + aoff + (size_t)(i0+row)*N + j0 + c0;
      short tmp[16];
      #pragma unroll
      for (int q = 0; q < 16; q += 4){
        float4 v = *(const float4*)(ap + q);
        tmp[q]=f2s(v.x); tmp[q+1]=f2s(v.y); tmp[q+2]=f2s(v.z); tmp[q+3]=f2s(v.w);
      }
      *(short8*)&sm.z.Adj[row*72 + c0]     = *(short8*)&tmp[0];
      *(short8*)&sm.z.Adj[row*72 + c0 + 8] = *(short8*)&tmp[8];
    } else {
      const short* ap = (const short*)p.adj + aoff + (size_t)(i0+row)*N + j0 + c0;
      *(short8*)&sm.z.Adj[row*72 + c0]     = *(const short8*)ap;
      *(short8*)&sm.z.Adj[row*72 + c0 + 8] = *(const short8*)(ap + 8);
    }
  }
  __syncthreads();
  int wave = tid >> 6, lane = tid & 63, m = lane & 15, kq = lane >> 4;
  int ra = wave*16 + m, sa = (ra >> 3) & 3;
  short8 a1 = *(const short8*)&sm.z.Zi[ra*72 + ((kq ^ sa) << 3)];
  short8 a2 = *(const short8*)&sm.z.Zi[ra*72 + (((kq+4) ^ sa) << 3)];
  f32x4 acc[4] = {};
  #pragma unroll
  for (int t4 = 0; t4 < 4; t4++){
    int rb = t4*16 + m, sb2 = (rb >> 3) & 3;
    short8 b1 = *(const short8*)&sm.z.Zj[rb*72 + ((kq ^ sb2) << 3)];
    short8 b2 = *(const short8*)&sm.z.Zj[rb*72 + (((kq+4) ^ sb2) << 3)];
    acc[t4] = __builtin_amdgcn_mfma_f32_16x16x32_bf16(a1, b1, acc[t4], 0, 0, 0);
    acc[t4] = __builtin_amdgcn_mfma_f32_16x16x32_bf16(a2, b2, acc[t4], 0, 0, 0);
  }
  float lts = 0.f, lP = 0.f, lQ = 0.f;
  #pragma unroll
  for (int t4 = 0; t4 < 4; t4++){
    int lj = t4*16 + m;
    #pragma unroll
    for (int reg = 0; reg < 4; reg++){
      int li = wave*16 + kq*4 + reg;
      float av = s2f(sm.z.Adj[li*72 + lj]);
      float dec = sigm(acc[t4][reg]);
      lts += av;
      lQ += (1.f - av)*log1pf(expf(dec));
      if (av != 0.f) lP += av*log1pf(expf(-dec));
    }
  }
  __syncthreads();
  sm.z.red[tid] = lts; __syncthreads();
  for (int o = 128; o > 0; o >>= 1){ if (tid < o) sm.z.red[tid] += sm.z.red[tid+o]; __syncthreads(); }
  if (tid == 0) atomicAdd(p.scal + 8 + t, sm.z.red[0]);
  __syncthreads();
  sm.z.red[tid] = lP; __syncthreads();
  for (int o = 128; o > 0; o >>= 1){ if (tid < o) sm.z.red[tid] += sm.z.red[tid+o]; __syncthreads(); }
  if (tid == 0) atomicAdd(p.scal + 12 + t, sm.z.red[0]);
  __syncthreads();
  sm.z.red[tid] = lQ; __syncthreads();
  for (int o = 128; o > 0; o >>= 1){ if (tid < o) sm.z.red[tid] += sm.z.red[tid+o]; __syncthreads(); }
  if (tid == 0) atomicAdd(p.scal + 16 + t, sm.z.red[0]);
}

// ---------------- setup kernels ----------------
__global__ __launch_bounds__(256) void setup0_k(KP p){
  int gb = blockIdx.x, tid = threadIdx.x;
  if (gb == 0){ if (tid < 64) p.scal[tid] = 0.f; }
  else if (gb == 1){
    if (tid == 0){
      const unsigned short* u = (const unsigned short*)p.x;
      int big = 0;
      for (int i = 0; i < 256; i++){ int e = (u[i] >> 7) & 0xFF; if (e >= 134) big++; }
      *p.dflag = (big > 16) ? 1 : 0;
    }
  } else {
    p.deg[(gb-2)*256 + tid] = 0;
  }
}

__global__ __launch_bounds__(256) void count_deg_k(KP p){
  int idx = blockIdx.x*256 + threadIdx.x;
  int t = idx >> 16, e = idx & (E-1);
  int dst = p.ei[(size_t)t*2*E + E + e] & (N-1);
  atomicAdd(&p.deg[t*N + dst], 1);
}

// scan+cursor (0-3) + h0 copy (4-35) + phi_x GEMM (36-1059, 1 tile each)
__global__ __launch_bounds__(256) void setup2_k(KP p){
  __shared__ SMem sm;
  int gb = blockIdx.x, tid = threadIdx.x;
  int f = *p.dflag;
  if (gb < 4){
    int t = gb;
    const int* dg = p.deg + t*N;
    int* of = p.offs + t*(N+1);
    int base = tid*16;
    int loc[16]; int s = 0;
    #pragma unroll
    for (int i = 0; i < 16; i++){ loc[i] = s; s += dg[base+i]; }
    sm.sh[tid] = s;
    __syncthreads();
    for (int o = 1; o < 256; o <<= 1){
      int v = (tid >= o) ? sm.sh[tid-o] : 0;
      __syncthreads();
      sm.sh[tid] += v;
      __syncthreads();
    }
    int pre = (tid == 0) ? 0 : sm.sh[tid-1];
    #pragma unroll
    for (int i = 0; i < 16; i++){
      int deg_i = dg[base+i];
      of[base+i] = pre + loc[i];
      p.dinv[t*N + base + i] = rsqrtf(1.f + (float)deg_i);
    }
    if (tid == 255) of[N] = sm.sh[255];
    __syncthreads();
    #pragma unroll
    for (int i = 0; i < 16; i++) p.deg[t*N + base + i] = pre + loc[i];  // cursor
  } else if (gb < 36){
    for (int idx = (gb-4)*256 + tid; idx < N*HD; idx += 32*256){
      float v = ldI(p.h0, idx, f);
      p.h_prev[idx] = v; p.h_bf[idx] = f2b(v);
    }
  } else {
    int u = gb - 36;
    int colblk = u & 3, rowblk = u >> 2;
    mfma_tile(sm, tid, f, p.x, 1, XD, nullptr, 0, 0, XD, XD,
              p.phi_x_w, HD, colblk*64, p.phi_x_b, 1,
              p.phiXa, HD, rowblk*64, colblk*64);
  }
}

__global__ __launch_bounds__(256) void scatter_k(KP p){
  int idx = blockIdx.x*256 + threadIdx.x;
  int t = idx >> 16, e = idx & (E-1);
  int s = p.ei[(size_t)t*2*E + e] & (N-1);
  int d = p.ei[(size_t)t*2*E + E + e] & (N-1);
  int pos = atomicAdd(&p.deg[t*N + d], 1);
  if (pos >= 0 && pos < E){
    p.srcs[(size_t)t*E + pos] = s;
    p.enorm[(size_t)t*E + pos] = p.dinv[t*N + s] * p.dinv[t*N + d];
  }
}

// ---------------- step kernels ----------------
__global__ __launch_bounds__(256) void g1_k(KP p, int t){   // grid 1024
  __shared__ SMem sm;
  int gb = blockIdx.x, tid = threadIdx.x, f = *p.dflag;
  const bf16* phiX = p.phiXa + (size_t)t*N*HD;
  int colblk = gb & 15, rowblk = gb >> 4;
  int grp = colblk >> 2, c4 = colblk & 3;
  if (grp == 0)
    mfma_tile(sm, tid, f, phiX, 2, HD, p.h_bf, 2, HD, 256, 512,
              p.enc_w, HD, c4*64, nullptr, 0, p.Gs1, 1024, rowblk*64, colblk*64);
  else if (grp == 1)
    mfma_tile(sm, tid, f, p.h_bf, 2, HD, nullptr, 0, 0, 256, 256,
              p.prior_w, HD, c4*64, p.prior_b, 1, p.Gs1, 1024, rowblk*64, colblk*64);
  else if (grp == 2)
    mfma_tile(sm, tid, f, p.h_bf, 2, HD, nullptr, 0, 0, 256, 256,
              p.ghz, HD, c4*64, nullptr, 0, p.Gs1, 1024, rowblk*64, colblk*64);
  else
    mfma_tile(sm, tid, f, p.h_bf, 2, HD, nullptr, 0, 0, 256, 256,
              p.ghr, HD, c4*64, nullptr, 0, p.Gs1, 1024, rowblk*64, colblk*64);
}

__global__ __launch_bounds__(256) void encagg_k(KP p, int t){   // grid 512
  int gb = blockIdx.x, tid = threadIdx.x, f = *p.dflag;
  const int* offs_t = p.offs + t*(N+1);
  const int* srcs_t = p.srcs + (size_t)t*E;
  const float* en_t = p.enorm + (size_t)t*E;
  const float* dv_t = p.dinv + t*N;
  int g8 = tid >> 5, l = tid & 31;
  int n = gb*8 + g8, c = l*8;
  int e0 = offs_t[n], e1 = offs_t[n+1];
  float d2 = dv_t[n]*dv_t[n];
  float acc[8], v[8];
  ld8b(p.Gs1 + (size_t)n*1024 + c, v);
  #pragma unroll
  for (int j = 0; j < 8; j++) acc[j] = d2 * v[j];
  for (int e = e0; e < e1; e++){
    int s = srcs_t[e] & (N-1);
    float nm = en_t[e];
    ld8b(p.Gs1 + (size_t)s*1024 + c, v);
    #pragma unroll
    for (int j = 0; j < 8; j++) acc[j] += nm * v[j];
  }
  #pragma unroll
  for (int j = 0; j < 8; j++) acc[j] = fmaxf(acc[j] + ldI(p.enc_b, c + j, f), 0.f);
  uint4 o; o.x = pack2(acc[0],acc[1]); o.y = pack2(acc[2],acc[3]);
  o.z = pack2(acc[4],acc[5]); o.w = pack2(acc[6],acc[7]);
  *(uint4*)(p.Tb1 + (size_t)n*HD + c) = o;
}

// fused: agg(Tb1) -> @[enc_mean|enc_std]w; prior_t @ [prior_mean|prior_std]w + b;
//        reparam + out_em/out_pm + kld; phi_z -> Tb2.   (grid 256, 16 nodes/block)
__global__ __launch_bounds__(256) void msagg_k(KP p, int t){
  __shared__ struct {
    float aggT[16*260];    // aggregated enc_t, f32
    short priorT[16*264];  // prior_t staged
    float msL[16*132];     // enc [mean|stdpre]
    float pmsL[16*132];    // prior [mean|stdpre] (bias applied)
    float zL[16*68];       // z f32
    float red[256];
  } sm;
  int gb = blockIdx.x, tid = threadIdx.x, f = *p.dflag;
  const int* offs_t = p.offs + t*(N+1);
  const int* srcs_t = p.srcs + (size_t)t*E;
  const float* en_t = p.enorm + (size_t)t*E;
  const float* dv_t = p.dinv + t*N;
  int nd = tid >> 4, l = tid & 15;
  int n = gb*16 + nd;
  // phase A: aggregate Tb1 (256 cols; 16 lanes x 16 cols)
  {
    int c = l*16;
    int e0 = offs_t[n], e1 = offs_t[n+1];
    float d2 = dv_t[n]*dv_t[n];
    float acc[16], v[8];
    ld8b(p.Tb1 + (size_t)n*HD + c, v);
    #pragma unroll
    for (int j = 0; j < 8; j++) acc[j] = d2*v[j];
    ld8b(p.Tb1 + (size_t)n*HD + c + 8, v);
    #pragma unroll
    for (int j = 0; j < 8; j++) acc[8+j] = d2*v[j];
    for (int e = e0; e < e1; e++){
      int s = srcs_t[e] & (N-1);
      float nm = en_t[e];
      ld8b(p.Tb1 + (size_t)s*HD + c, v);
      #pragma unroll
      for (int j = 0; j < 8; j++) acc[j] += nm*v[j];
      ld8b(p.Tb1 + (size_t)s*HD + c + 8, v);
      #pragma unroll
      for (int j = 0; j < 8; j++) acc[8+j] += nm*v[j];
    }
    #pragma unroll
    for (int j = 0; j < 16; j++) sm.aggT[nd*260 + c + j] = acc[j];
    // stage prior_t (bf16) from Gs1 cols 256..511
    *(short8*)&sm.priorT[nd*264 + l*16] =
        *(const short8*)((const short*)p.Gs1 + (size_t)n*1024 + 256 + l*16);
    *(short8*)&sm.priorT[nd*264 + l*16 + 8] =
        *(const short8*)((const short*)p.Gs1 + (size_t)n*1024 + 256 + l*16 + 8);
  }
  __syncthreads();
  // phase B: enc-ms = aggT @ [mean|std]w  (out cols 0..127)
  {
    int c8 = l*8;
    const void* W = (c8 < 64) ? p.enc_mean_w : p.enc_std_w;
    int wc = c8 & 63;
    float acc[8] = {};
    #pragma unroll 4
    for (int k = 0; k < 256; k++){
      float a = sm.aggT[nd*260 + k];
      float w[8]; ldW8(W, (size_t)k*ZD + wc, f, w);
      #pragma unroll
      for (int j = 0; j < 8; j++) acc[j] += a*w[j];
    }
    #pragma unroll
    for (int j = 0; j < 8; j++) sm.msL[nd*132 + c8 + j] = acc[j];
  }
  // phase C: prior-ms = prior_t @ [mean|std]w + b
  {
    int c8 = l*8;
    const void* W = (c8 < 64) ? p.prior_mean_w : p.prior_std_w;
    const void* B = (c8 < 64) ? p.prior_mean_b : p.prior_std_b;
    int wc = c8 & 63;
    float acc[8] = {};
    #pragma unroll 4
    for (int k = 0; k < 256; k++){
      float a = s2f(sm.priorT[nd*264 + k]);
      float w[8]; ldW8(W, (size_t)k*ZD + wc, f, w);
      #pragma unroll
      for (int j = 0; j < 8; j++) acc[j] += a*w[j];
    }
    #pragma unroll
    for (int j = 0; j < 8; j++) sm.pmsL[nd*132 + c8 + j] = acc[j] + ldI(B, wc + j, f);
  }
  __syncthreads();
  // phase D: reparam + outputs + kld partial
  float el = 0.f;
  {
    int d0 = l*4;
    #pragma unroll
    for (int q = 0; q < 4; q++){
      int d = d0 + q;
      size_t idx = (size_t)n*ZD + d;
      float mean = sm.msL[nd*132 + d] + ldI(p.enc_mean_b, d, f);
      float sd = splus(sm.msL[nd*132 + 64 + d] + ldI(p.enc_std_b, d, f));
      float zv = ldI(p.eps, (size_t)t*N*ZD + idx, f)*sd + mean;
      sm.zL[nd*68 + d] = zv;
      p.zbf[idx] = f2b(zv);
      stO(p.out, OUT_EM + (size_t)t*N*ZD + idx, mean, f);
      float pm = sm.pmsL[nd*132 + d];
      float ps = splus(sm.pmsL[nd*132 + 64 + d]);
      stO(p.out, OUT_PM + (size_t)t*N*ZD + idx, pm, f);
      float s1 = sd + 1e-10f, s2 = ps + 1e-10f;
      float dm = mean - pm;
      el += 2.f*(logf(s2) - logf(s1)) - (s1*s1 + dm*dm)/(s2*s2) + 1.f;
    }
  }
  __syncthreads();
  // phase E: phi_z = relu(z @ phi_z_w + b) -> Tb2 (16 cols/thread)
  {
    int c0 = l*16;
    float acc[16] = {};
    #pragma unroll 4
    for (int k = 0; k < 64; k++){
      float zk = sm.zL[nd*68 + k];
      float w[8];
      ldW8(p.phi_z_w, (size_t)k*HD + c0, f, w);
      #pragma unroll
      for (int j = 0; j < 8; j++) acc[j] += zk*w[j];
      ldW8(p.phi_z_w, (size_t)k*HD + c0 + 8, f, w);
      #pragma unroll
      for (int j = 0; j < 8; j++) acc[8+j] += zk*w[j];
    }
    #pragma unroll
    for (int j = 0; j < 16; j++)
      acc[j] = fmaxf(acc[j] + ldI(p.phi_z_b, c0 + j, f), 0.f);
    uint4 o0, o1;
    o0.x = pack2(acc[0],acc[1]);  o0.y = pack2(acc[2],acc[3]);
    o0.z = pack2(acc[4],acc[5]);  o0.w = pack2(acc[6],acc[7]);
    o1.x = pack2(acc[8],acc[9]);  o1.y = pack2(acc[10],acc[11]);
    o1.z = pack2(acc[12],acc[13]); o1.w = pack2(acc[14],acc[15]);
    *(uint4*)(p.Tb2 + (size_t)n*HD + c0) = o0;
    *(uint4*)(p.Tb2 + (size_t)n*HD + c0 + 8) = o1;
  }
  // kld reduce
  sm.red[tid] = el; __syncthreads();
  for (int o = 128; o > 0; o >>= 1){ if (tid < o) sm.red[tid] += sm.red[tid+o]; __syncthreads(); }
  if (tid == 0) atomicAdd(p.scal + 4, sm.red[0] * (0.5f/((float)N*(float)ZD)));
}

// gru-x GEMM (0-767) + dec tiles (768-4863)
__global__ __launch_bounds__(256) void grux_dec_k(KP p, int t){   // grid 4864
  __shared__ SMem sm;
  int gb = blockIdx.x, tid = threadIdx.x, f = *p.dflag;
  if (gb < 768){
    const bf16* phiX = p.phiXa + (size_t)t*N*HD;
    int colblk = gb % 12, rowblk = gb / 12;
    int grp = colblk >> 2, c4 = colblk & 3;
    const void* W = (grp == 0) ? p.gxz : ((grp == 1) ? p.gxr : p.gxh);
    mfma_tile(sm, tid, f, phiX, 2, HD, p.Tb2, 2, HD, 256, 512,
              W, HD, c4*64, nullptr, 0, p.Gsx, 768, rowblk*64, colblk*64);
  } else {
    dec_tile1(p, sm, tid, t, gb - 768, f);
  }
}

__global__ __launch_bounds__(256) void zr_k(KP p, int t){   // grid 1024
  int gb = blockIdx.x, tid = threadIdx.x;
  const int* offs_t = p.offs + t*(N+1);
  const int* srcs_t = p.srcs + (size_t)t*E;
  const float* en_t = p.enorm + (size_t)t*E;
  const float* dv_t = p.dinv + t*N;
  int g4 = tid >> 6, lane = tid & 63;
  int n = gb*4 + g4, c = lane*8;
  int e0 = offs_t[n], e1 = offs_t[n+1];
  float d2 = dv_t[n]*dv_t[n];
  float acc[8], v1[8], v2[8];
  ld8b(p.Gsx + (size_t)n*768 + c, v1);
  ld8b(p.Gs1 + 512 + (size_t)n*1024 + c, v2);
  #pragma unroll
  for (int j = 0; j < 8; j++) acc[j] = d2 * (v1[j] + v2[j]);
  for (int e = e0; e < e1; e++){
    int s = srcs_t[e] & (N-1);
    float nm = en_t[e];
    ld8b(p.Gsx + (size_t)s*768 + c, v1);
    ld8b(p.Gs1 + 512 + (size_t)s*1024 + c, v2);
    #pragma unroll
    for (int j = 0; j < 8; j++) acc[j] += nm * (v1[j] + v2[j]);
  }
  if (c < 256){
    size_t base = (size_t)n*HD + c;
    float4 o0, o1;
    o0.x = sigm(acc[0]); o0.y = sigm(acc[1]); o0.z = sigm(acc[2]); o0.w = sigm(acc[3]);
    o1.x = sigm(acc[4]); o1.y = sigm(acc[5]); o1.z = sigm(acc[6]); o1.w = sigm(acc[7]);
    *(float4*)(p.z_g + base) = o0;
    *(float4*)(p.z_g + base + 4) = o1;
  } else {
    size_t base = (size_t)n*HD + (c - 256);
    float r[8];
    #pragma unroll
    for (int j = 0; j < 8; j++) r[j] = sigm(acc[j]) * p.h_prev[base+j];
    uint4 o; o.x = pack2(r[0],r[1]); o.y = pack2(r[2],r[3]);
    o.z = pack2(r[4],r[5]); o.w = pack2(r[6],r[7]);
    *(uint4*)(p.Tb1 + base) = o;
  }
}

__global__ __launch_bounds__(256) void hh_k(KP p, int t){   // grid 256
  __shared__ SMem sm;
  int gb = blockIdx.x, tid = threadIdx.x, f = *p.dflag;
  int colblk = gb & 3, rowblk = gb >> 2;
  mfma_tile(sm, tid, f, p.Tb1, 2, HD, nullptr, 0, 0, 256, 256,
            p.ghh, HD, colblk*64, nullptr, 0, p.Gh2, 256, rowblk*64, colblk*64);
}

// h update (0-511); at t==3, block 512 finalizes kld/nll outputs
__global__ __launch_bounds__(256) void hagg_k(KP p, int t){
  int gb = blockIdx.x, tid = threadIdx.x, f = *p.dflag;
  if (gb >= 512){
    if (tid == 0){
      const float NNf = 16777216.f;
      float nll = 0.f;
      for (int tt = 0; tt < T_STEPS; tt++){
        float ts = p.scal[8+tt], P = p.scal[12+tt], Q = p.scal[16+tt];
        float posw = (NNf - ts)/ts;
        nll += (posw*P + Q) * 0.5f/(NNf - ts);
      }
      stO(p.out, 0, p.scal[4], f);
      stO(p.out, 1, nll, f);
    }
    return;
  }
  const int* offs_t = p.offs + t*(N+1);
  const int* srcs_t = p.srcs + (size_t)t*E;
  const float* en_t = p.enorm + (size_t)t*E;
  const float* dv_t = p.dinv + t*N;
  int g8 = tid >> 5, l = tid & 31;
  int n = gb*8 + g8, c = l*8;
  int e0 = offs_t[n], e1 = offs_t[n+1];
  float d2 = dv_t[n]*dv_t[n];
  float acc[8], v1[8], v2[8];
  ld8b(p.Gsx + 512 + (size_t)n*768 + c, v1);
  ld8b(p.Gh2 + (size_t)n*256 + c, v2);
  #pragma unroll
  for (int j = 0; j < 8; j++) acc[j] = d2 * (v1[j] + v2[j]);
  for (int e = e0; e < e1; e++){
    int s = srcs_t[e] & (N-1);
    float nm = en_t[e];
    ld8b(p.Gsx + 512 + (size_t)s*768 + c, v1);
    ld8b(p.Gh2 + (size_t)s*256 + c, v2);
    #pragma unroll
    for (int j = 0; j < 8; j++) acc[j] += nm * (v1[j] + v2[j]);
  }
  size_t base = (size_t)n*HD + c;
  #pragma unroll
  for (int j = 0; j < 8; j++){
    float z = p.z_g[base+j];
    float hv = p.h_prev[base+j];
    float nv = z*hv + (1.f - z)*tanhf(acc[j]);
    p.h_prev[base+j] = nv;
    p.h_bf[base+j] = f2b(nv);
    if (t == T_STEPS-1) stO(p.out, OUT_H + base + j, nv, f);
  }
}

// ---------------- host ----------------
extern "C" void kernel_launch(void* const* d_in, const int* in_sizes, int n_in,
                              void* d_out, int out_size, void* d_ws, size_t ws_size,
                              hipStream_t stream){
  KP P;
  P.x = d_in[0];  P.ei = (const int*)d_in[1];  P.adj = d_in[2];  P.eps = d_in[3];  P.h0 = d_in[4];
  P.phi_x_w = d_in[5];  P.phi_x_b = d_in[6];  P.phi_z_w = d_in[7];  P.phi_z_b = d_in[8];
  P.enc_w = d_in[9];  P.enc_b = d_in[10];
  P.enc_mean_w = d_in[11];  P.enc_mean_b = d_in[12];
  P.enc_std_w = d_in[13];   P.enc_std_b = d_in[14];
  P.prior_w = d_in[15];  P.prior_b = d_in[16];
  P.prior_mean_w = d_in[17];  P.prior_mean_b = d_in[18];
  P.prior_std_w = d_in[19];   P.prior_std_b = d_in[20];
  P.gxz = d_in[21];  P.ghz = d_in[22];  P.gxr = d_in[23];
  P.ghr = d_in[24];  P.gxh = d_in[25];  P.ghh = d_in[26];
  P.out = d_out;

  char* wp = (char*)d_ws;
  auto alloc = [&](size_t bytes){ void* q = (void*)wp; wp += (bytes + 255) & ~(size_t)255; return q; };
  P.scal  = (float*)alloc(64*sizeof(float));
  P.dflag = (int*)  alloc(256);
  P.dinv  = (float*)alloc((size_t)T_STEPS*N*4);
  P.offs  = (int*)  alloc((size_t)T_STEPS*(N+1)*4);
  P.srcs  = (int*)  alloc((size_t)T_STEPS*E*4);
  P.enorm = (float*)alloc((size_t)T_STEPS*E*4);
  P.deg   = (int*)  alloc((size_t)T_STEPS*N*4);
  P.h_prev= (float*)alloc((size_t)N*HD*4);
  P.h_bf  = (bf16*) alloc((size_t)N*HD*2);
  P.phiXa = (bf16*) alloc((size_t)T_STEPS*N*HD*2);
  P.Tb1   = (bf16*) alloc((size_t)N*HD*2);
  P.Tb2   = (bf16*) alloc((size_t)N*HD*2);
  P.zbf   = (bf16*) alloc((size_t)N*ZD*2);
  P.z_g   = (float*)alloc((size_t)N*HD*4);
  P.Gs1   = (bf16*) alloc((size_t)N*1024*2);
  P.Gsx   = (bf16*) alloc((size_t)N*768*2);
  P.Gh2   = (bf16*) alloc((size_t)N*256*2);

  setup0_k<<<66,256,0,stream>>>(P);
  count_deg_k<<<1024,256,0,stream>>>(P);
  setup2_k<<<1060,256,0,stream>>>(P);
  scatter_k<<<1024,256,0,stream>>>(P);
  for (int t = 0; t < T_STEPS; t++){
    g1_k<<<1024,256,0,stream>>>(P, t);
    encagg_k<<<512,256,0,stream>>>(P, t);
    msagg_k<<<256,256,0,stream>>>(P, t);
    grux_dec_k<<<4864,256,0,stream>>>(P, t);
    zr_k<<<1024,256,0,stream>>>(P, t);
    hh_k<<<256,256,0,stream>>>(P, t);
    hagg_k<<<(t == T_STEPS-1) ? 513 : 512,256,0,stream>>>(P, t);
  }
}

// Round 11
// 1663.514 us; speedup vs baseline: 1.2510x; 1.2510x over previous
//
#include <hip/hip_runtime.h>
#include <hip/hip_bf16.h>

#define T_STEPS 4
#define N 4096
#define E 65536
#define XD 256
#define HD 256
#define ZD 64

typedef __hip_bfloat16 bf16;
typedef __attribute__((ext_vector_type(8))) short short8;
typedef __attribute__((ext_vector_type(4))) float f32x4;

__device__ __forceinline__ float b2f(bf16 v){ return __bfloat162float(v); }
__device__ __forceinline__ bf16 f2b(float v){ return __float2bfloat16(v); }
__device__ __forceinline__ short f2s(float v){ return __builtin_bit_cast(short, f2b(v)); }
__device__ __forceinline__ float bits2f(unsigned int s){ return __builtin_bit_cast(float, s << 16); }
__device__ __forceinline__ float s2f(short s){ return bits2f((unsigned int)(unsigned short)s); }
__device__ __forceinline__ float splus(float x){ return (x > 20.f) ? x : log1pf(expf(x)); }
__device__ __forceinline__ float sigm(float x){ return 1.f/(1.f + expf(-x)); }

__device__ __forceinline__ float ldI(const void* p, size_t i, int f){
  return f ? ((const float*)p)[i] : b2f(((const bf16*)p)[i]);
}
__device__ __forceinline__ void stO(void* p, size_t i, float v, int f){
  if (f) ((float*)p)[i] = v; else ((bf16*)p)[i] = f2b(v);
}
__device__ __forceinline__ void ld8b(const bf16* p, float v[8]){
  uint4 u = *(const uint4*)p;
  v[0]=bits2f(u.x & 0xffffu); v[1]=bits2f(u.x >> 16);
  v[2]=bits2f(u.y & 0xffffu); v[3]=bits2f(u.y >> 16);
  v[4]=bits2f(u.z & 0xffffu); v[5]=bits2f(u.z >> 16);
  v[6]=bits2f(u.w & 0xffffu); v[7]=bits2f(u.w >> 16);
}
__device__ __forceinline__ void ldW8(const void* W, size_t off, int f, float w[8]){
  if (f == 0){ ld8b((const bf16*)W + off, w); }
  else {
    const float* Wf = (const float*)W + off;
    float4 a = *(const float4*)Wf, b = *(const float4*)(Wf + 4);
    w[0]=a.x; w[1]=a.y; w[2]=a.z; w[3]=a.w; w[4]=b.x; w[5]=b.y; w[6]=b.z; w[7]=b.w;
  }
}
__device__ __forceinline__ unsigned int pack2(float a, float b){
  return (unsigned int)(unsigned short)__builtin_bit_cast(unsigned short, f2b(a))
       | ((unsigned int)(unsigned short)__builtin_bit_cast(unsigned short, f2b(b)) << 16);
}
__device__ __forceinline__ uint4 pack8(const float v[8]){
  uint4 o; o.x = pack2(v[0],v[1]); o.y = pack2(v[2],v[3]);
  o.z = pack2(v[4],v[5]); o.w = pack2(v[6],v[7]);
  return o;
}

union SMem {
  struct { short As[64*40]; short Wt[64*40]; } g;                        // 10.2 KB (GEMM)
  struct { short Zi[64*72]; short Zj[64*72]; short Adj[64*72]; float red[256]; } z; // 28.7 KB
  int sh[256];
  float red[256];
};

struct KP {
  const void *x, *adj, *eps, *h0;
  const int* ei;
  const void *phi_x_w, *phi_x_b, *phi_z_w, *phi_z_b;
  const void *enc_w, *enc_b, *enc_mean_w, *enc_mean_b, *enc_std_w, *enc_std_b;
  const void *prior_w, *prior_b, *prior_mean_w, *prior_mean_b, *prior_std_w, *prior_std_b;
  const void *gxz, *ghz, *gxr, *ghr, *gxh, *ghh;
  void* out;
  float* scal; int* dflag; float* dinv; int* offs; int* srcs; float* enorm; int* deg;
  float* h_prev; bf16* h_bf; bf16* phiXa; bf16* Tb2;
  bf16* zbf; float* z_g; bf16* Gs1; bf16* Gsx; bf16* Gms; bf16* Gh2;
};

#define OUT_EM ((size_t)2)
#define OUT_PM ((size_t)(2 + (size_t)T_STEPS*N*ZD))
#define OUT_H  ((size_t)(2 + (size_t)2*T_STEPS*N*ZD))

// ---------------- MFMA 64x64 tile: C = [A1|A2] @ W(+bias)(+relu), bf16 out ----------------
__device__ void mfma_tile(SMem& sm, int tid, int f,
    const void* A1, int am1, int lda1, const void* A2, int am2, int lda2,
    int K1, int K, const void* W, int ldw, int wcol,
    const void* bias, int act, bf16* C, int ldc, int row0, int ccol0){
  int ar = tid >> 2, akk = (tid & 3)*8;
  int wk = tid >> 3, wn = (tid & 7)*8;
  int wave = tid >> 6, lane = tid & 63, m = lane & 15, kq = lane >> 4;
  f32x4 acc[4] = {};
  for (int k0 = 0; k0 < K; k0 += 32){
    const void* A; int am, lda, kb;
    if (k0 < K1){ A = A1; am = am1; lda = lda1; kb = k0; }
    else        { A = A2; am = am2; lda = lda2; kb = k0 - K1; }
    size_t aidx = (size_t)(row0 + ar)*lda + kb + akk;
    short8 av;
    if (am == 2 || (am == 1 && f == 0)){
      av = *(const short8*)((const short*)A + aidx);
    } else {
      const float* Af = (const float*)A;
      float4 u0 = *(const float4*)(Af + aidx);
      float4 u1 = *(const float4*)(Af + aidx + 4);
      av[0]=f2s(u0.x); av[1]=f2s(u0.y); av[2]=f2s(u0.z); av[3]=f2s(u0.w);
      av[4]=f2s(u1.x); av[5]=f2s(u1.y); av[6]=f2s(u1.z); av[7]=f2s(u1.w);
    }
    *(short8*)&sm.g.As[ar*40 + akk] = av;
    size_t wi = (size_t)(k0 + wk)*ldw + wcol + wn;
    float wf[8]; short wv[8];
    if (f == 0){
      short8 t8 = *(const short8*)((const short*)W + wi);
      #pragma unroll
      for (int j = 0; j < 8; j++) wv[j] = t8[j];
    } else {
      ldW8(W, wi, f, wf);
      #pragma unroll
      for (int j = 0; j < 8; j++) wv[j] = f2s(wf[j]);
    }
    #pragma unroll
    for (int j = 0; j < 8; j++){
      int nrow = wn + j;
      int col = (((wk >> 3) ^ ((nrow >> 3) & 3)) << 3) | (wk & 7);
      sm.g.Wt[nrow*40 + col] = wv[j];
    }
    __syncthreads();
    short8 afr = *(const short8*)&sm.g.As[(wave*16 + m)*40 + kq*8];
    #pragma unroll
    for (int t4 = 0; t4 < 4; t4++){
      int nb = t4*16 + m;
      short8 bfr = *(const short8*)&sm.g.Wt[nb*40 + ((kq ^ ((nb >> 3) & 3)) << 3)];
      acc[t4] = __builtin_amdgcn_mfma_f32_16x16x32_bf16(afr, bfr, acc[t4], 0, 0, 0);
    }
    __syncthreads();
  }
  #pragma unroll
  for (int t4 = 0; t4 < 4; t4++){
    int c = ccol0 + t4*16 + m;
    float bv = bias ? ldI(bias, wcol + t4*16 + m, f) : 0.f;
    #pragma unroll
    for (int reg = 0; reg < 4; reg++){
      int r = row0 + wave*16 + kq*4 + reg;
      float v = acc[t4][reg] + bv;
      if (act == 1) v = fmaxf(v, 0.f);
      C[(size_t)r*ldc + c] = f2b(v);
    }
  }
}

// ---------------- dec 64x64 tile via MFMA, adj through LDS ----------------
__device__ void dec_tile1(const KP& p, SMem& sm, int tid, int t, int u, int f){
  int i0 = (u >> 6)*64, j0 = (u & 63)*64;
  size_t aoff = (size_t)t*N*N;
  #pragma unroll
  for (int i = 0; i < 2; i++){
    int idx = tid + i*256;
    int r = idx >> 3, c = idx & 7;
    int col = ((c ^ ((r >> 3) & 3)) << 3);
    *(short8*)&sm.z.Zi[r*72 + col] = *(const short8*)((const short*)p.zbf + (size_t)(i0+r)*ZD + c*8);
    *(short8*)&sm.z.Zj[r*72 + col] = *(const short8*)((const short*)p.zbf + (size_t)(j0+r)*ZD + c*8);
  }
  {
    int row = tid >> 2, c0 = (tid & 3)*16;
    if (f){
      const float* ap = (const float*)p.adj + aoff + (size_t)(i0+row)*N + j0 + c0;
      short tmp[16];
      #pragma unroll
      for (int q = 0; q < 16; q += 4){
        float4 v = *(const float4*)(ap + q);
        tmp[q]=f2s(v.x); tmp[q+1]=f2s(v.y); tmp[q+2]=f2s(v.z); tmp[q+3]=f2s(v.w);
      }
      *(short8*)&sm.z.Adj[row*72 + c0]     = *(short8*)&tmp[0];
      *(short8*)&sm.z.Adj[row*72 + c0 + 8] = *(short8*)&tmp[8];
    } else {
      const short* ap = (const short*)p.adj + aoff + (size_t)(i0+row)*N + j0 + c0;
      *(short8*)&sm.z.Adj[row*72 + c0]     = *(const short8*)ap;
      *(short8*)&sm.z.Adj[row*72 + c0 + 8] = *(const short8*)(ap + 8);
    }
  }
  __syncthreads();
  int wave = tid >> 6, lane = tid & 63, m = lane & 15, kq = lane >> 4;
  int ra = wave*16 + m, sa = (ra >> 3) & 3;
  short8 a1 = *(const short8*)&sm.z.Zi[ra*72 + ((kq ^ sa) << 3)];
  short8 a2 = *(const short8*)&sm.z.Zi[ra*72 + (((kq+4) ^ sa) << 3)];
  f32x4 acc[4] = {};
  #pragma unroll
  for (int t4 = 0; t4 < 4; t4++){
    int rb = t4*16 + m, sb2 = (rb >> 3) & 3;
    short8 b1 = *(const short8*)&sm.z.Zj[rb*72 + ((kq ^ sb2) << 3)];
    short8 b2 = *(const short8*)&sm.z.Zj[rb*72 + (((kq+4) ^ sb2) << 3)];
    acc[t4] = __builtin_amdgcn_mfma_f32_16x16x32_bf16(a1, b1, acc[t4], 0, 0, 0);
    acc[t4] = __builtin_amdgcn_mfma_f32_16x16x32_bf16(a2, b2, acc[t4], 0, 0, 0);
  }
  float lts = 0.f, lP = 0.f, lQ = 0.f;
  #pragma unroll
  for (int t4 = 0; t4 < 4; t4++){
    int lj = t4*16 + m;
    #pragma unroll
    for (int reg = 0; reg < 4; reg++){
      int li = wave*16 + kq*4 + reg;
      float av = s2f(sm.z.Adj[li*72 + lj]);
      float dec = sigm(acc[t4][reg]);
      lts += av;
      lQ += (1.f - av)*log1pf(expf(dec));
      if (av != 0.f) lP += av*log1pf(expf(-dec));
    }
  }
  __syncthreads();
  sm.z.red[tid] = lts; __syncthreads();
  for (int o = 128; o > 0; o >>= 1){ if (tid < o) sm.z.red[tid] += sm.z.red[tid+o]; __syncthreads(); }
  if (tid == 0) atomicAdd(p.scal + 8 + t, sm.z.red[0]);
  __syncthreads();
  sm.z.red[tid] = lP; __syncthreads();
  for (int o = 128; o > 0; o >>= 1){ if (tid < o) sm.z.red[tid] += sm.z.red[tid+o]; __syncthreads(); }
  if (tid == 0) atomicAdd(p.scal + 12 + t, sm.z.red[0]);
  __syncthreads();
  sm.z.red[tid] = lQ; __syncthreads();
  for (int o = 128; o > 0; o >>= 1){ if (tid < o) sm.z.red[tid] += sm.z.red[tid+o]; __syncthreads(); }
  if (tid == 0) atomicAdd(p.scal + 16 + t, sm.z.red[0]);
}

// ---------------- setup kernels ----------------
__global__ __launch_bounds__(256) void setup0_k(KP p){
  int gb = blockIdx.x, tid = threadIdx.x;
  if (gb == 0){ if (tid < 64) p.scal[tid] = 0.f; }
  else if (gb == 1){
    if (tid == 0){
      const unsigned short* u = (const unsigned short*)p.x;
      int big = 0;
      for (int i = 0; i < 256; i++){ int e = (u[i] >> 7) & 0xFF; if (e >= 134) big++; }
      *p.dflag = (big > 16) ? 1 : 0;
    }
  } else {
    p.deg[(gb-2)*256 + tid] = 0;
  }
}

__global__ __launch_bounds__(256) void count_deg_k(KP p){
  int idx = blockIdx.x*256 + threadIdx.x;
  int t = idx >> 16, e = idx & (E-1);
  int dst = p.ei[(size_t)t*2*E + E + e] & (N-1);
  atomicAdd(&p.deg[t*N + dst], 1);
}

// scan+cursor (0-3) + h0 copy (4-35) + phi_x GEMM (36-1059)
__global__ __launch_bounds__(256) void setup2_k(KP p){
  __shared__ SMem sm;
  int gb = blockIdx.x, tid = threadIdx.x;
  int f = *p.dflag;
  if (gb < 4){
    int t = gb;
    const int* dg = p.deg + t*N;
    int* of = p.offs + t*(N+1);
    int base = tid*16;
    int loc[16]; int s = 0;
    #pragma unroll
    for (int i = 0; i < 16; i++){ loc[i] = s; s += dg[base+i]; }
    sm.sh[tid] = s;
    __syncthreads();
    for (int o = 1; o < 256; o <<= 1){
      int v = (tid >= o) ? sm.sh[tid-o] : 0;
      __syncthreads();
      sm.sh[tid] += v;
      __syncthreads();
    }
    int pre = (tid == 0) ? 0 : sm.sh[tid-1];
    #pragma unroll
    for (int i = 0; i < 16; i++){
      int deg_i = dg[base+i];
      of[base+i] = pre + loc[i];
      p.dinv[t*N + base + i] = rsqrtf(1.f + (float)deg_i);
    }
    if (tid == 255) of[N] = sm.sh[255];
    __syncthreads();
    #pragma unroll
    for (int i = 0; i < 16; i++) p.deg[t*N + base + i] = pre + loc[i];  // cursor
  } else if (gb < 36){
    for (int idx = (gb-4)*256 + tid; idx < N*HD; idx += 32*256){
      float v = ldI(p.h0, idx, f);
      p.h_prev[idx] = v; p.h_bf[idx] = f2b(v);
    }
  } else {
    int u = gb - 36;
    int colblk = u & 3, rowblk = u >> 2;
    mfma_tile(sm, tid, f, p.x, 1, XD, nullptr, 0, 0, XD, XD,
              p.phi_x_w, HD, colblk*64, p.phi_x_b, 1,
              p.phiXa, HD, rowblk*64, colblk*64);
  }
}

__global__ __launch_bounds__(256) void scatter_k(KP p){
  int idx = blockIdx.x*256 + threadIdx.x;
  int t = idx >> 16, e = idx & (E-1);
  int s = p.ei[(size_t)t*2*E + e] & (N-1);
  int d = p.ei[(size_t)t*2*E + E + e] & (N-1);
  int pos = atomicAdd(&p.deg[t*N + d], 1);
  if (pos >= 0 && pos < E){
    p.srcs[(size_t)t*E + pos] = s;
    p.enorm[(size_t)t*E + pos] = p.dinv[t*N + s] * p.dinv[t*N + d];
  }
}

// ---------------- step kernels ----------------
__global__ __launch_bounds__(256) void g1_k(KP p, int t){   // grid 1024
  __shared__ SMem sm;
  int gb = blockIdx.x, tid = threadIdx.x, f = *p.dflag;
  const bf16* phiX = p.phiXa + (size_t)t*N*HD;
  int colblk = gb & 15, rowblk = gb >> 4;
  int grp = colblk >> 2, c4 = colblk & 3;
  if (grp == 0)
    mfma_tile(sm, tid, f, phiX, 2, HD, p.h_bf, 2, HD, 256, 512,
              p.enc_w, HD, c4*64, nullptr, 0, p.Gs1, 1024, rowblk*64, colblk*64);
  else if (grp == 1)
    mfma_tile(sm, tid, f, p.h_bf, 2, HD, nullptr, 0, 0, 256, 256,
              p.prior_w, HD, c4*64, p.prior_b, 1, p.Gs1, 1024, rowblk*64, colblk*64);
  else if (grp == 2)
    mfma_tile(sm, tid, f, p.h_bf, 2, HD, nullptr, 0, 0, 256, 256,
              p.ghz, HD, c4*64, nullptr, 0, p.Gs1, 1024, rowblk*64, colblk*64);
  else
    mfma_tile(sm, tid, f, p.h_bf, 2, HD, nullptr, 0, 0, 256, 256,
              p.ghr, HD, c4*64, nullptr, 0, p.Gs1, 1024, rowblk*64, colblk*64);
}

// encagg: agg(Gs1 cols 0-255)+b+relu -> enc_t (LDS); project enc-ms (cols 0-127)
//         and prior-ms (cols 128-255, +bias) with LDS-staged weights -> Gms.   grid 512
__global__ __launch_bounds__(256) void encagg_k(KP p, int t){
  __shared__ struct {
    short encT[8*264];
    short priorT[8*264];
    short Wc[32*264];
  } sm;
  int gb = blockIdx.x, tid = threadIdx.x, f = *p.dflag;
  const int* offs_t = p.offs + t*(N+1);
  const int* srcs_t = p.srcs + (size_t)t*E;
  const float* en_t = p.enorm + (size_t)t*E;
  const float* dv_t = p.dinv + t*N;
  int g8 = tid >> 5, l = tid & 31;
  int n = gb*8 + g8, c = l*8;
  {
    int e0 = offs_t[n], e1 = offs_t[n+1];
    float d2 = dv_t[n]*dv_t[n];
    float acc[8], v[8];
    ld8b(p.Gs1 + (size_t)n*1024 + c, v);
    #pragma unroll
    for (int j = 0; j < 8; j++) acc[j] = d2 * v[j];
    for (int e = e0; e < e1; e++){
      int s = srcs_t[e] & (N-1);
      float nm = en_t[e];
      ld8b(p.Gs1 + (size_t)s*1024 + c, v);
      #pragma unroll
      for (int j = 0; j < 8; j++) acc[j] += nm * v[j];
    }
    #pragma unroll
    for (int j = 0; j < 8; j++) acc[j] = fmaxf(acc[j] + ldI(p.enc_b, c + j, f), 0.f);
    *(uint4*)&sm.encT[g8*264 + c] = pack8(acc);
    *(short8*)&sm.priorT[g8*264 + c] =
        *(const short8*)((const short*)p.Gs1 + (size_t)n*1024 + 256 + c);
  }
  __syncthreads();
  int nd = tid >> 5, c2 = (tid & 31)*8;
  const short* Arow = (c2 < 128) ? &sm.encT[nd*264] : &sm.priorT[nd*264];
  float acc2[8] = {};
  for (int k0 = 0; k0 < 256; k0 += 32){
    #pragma unroll
    for (int i = 0; i < 4; i++){
      int slot = tid + i*256;
      int kk = slot >> 5, cg = (slot & 31)*8;
      const void* W; int wc;
      if (cg < 64){ W = p.enc_mean_w; wc = cg; }
      else if (cg < 128){ W = p.enc_std_w; wc = cg - 64; }
      else if (cg < 192){ W = p.prior_mean_w; wc = cg - 128; }
      else { W = p.prior_std_w; wc = cg - 192; }
      float w[8]; ldW8(W, (size_t)(k0+kk)*ZD + wc, f, w);
      *(uint4*)&sm.Wc[kk*264 + cg] = pack8(w);
    }
    __syncthreads();
    #pragma unroll 8
    for (int kk = 0; kk < 32; kk++){
      float a = s2f(Arow[k0 + kk]);
      float w[8]; ld8b((const bf16*)&sm.Wc[kk*264 + c2], w);
      #pragma unroll
      for (int j = 0; j < 8; j++) acc2[j] += a*w[j];
    }
    __syncthreads();
  }
  if (c2 >= 128){
    const void* B = (c2 < 192) ? p.prior_mean_b : p.prior_std_b;
    int bc = (c2 < 192) ? (c2 - 128) : (c2 - 192);
    #pragma unroll
    for (int j = 0; j < 8; j++) acc2[j] += ldI(B, bc + j, f);
  }
  *(uint4*)(p.Gms + (size_t)(gb*8 + nd)*256 + c2) = pack8(acc2);
}

// msaggpost: agg Gms[0:128] + reparam + out_em/out_pm + kld + phi_z -> Tb2.  grid 256
__global__ __launch_bounds__(256) void msaggpost_k(KP p, int t){
  __shared__ struct {
    float msh[16*132];
    float zL[16*68];
    short Wc[16*264];
    float red[256];
  } sm;
  int gb = blockIdx.x, tid = threadIdx.x, f = *p.dflag;
  const int* offs_t = p.offs + t*(N+1);
  const int* srcs_t = p.srcs + (size_t)t*E;
  const float* en_t = p.enorm + (size_t)t*E;
  const float* dv_t = p.dinv + t*N;
  int nd = tid >> 4, l = tid & 15;
  int n = gb*16 + nd;
  {
    int c = l*8;
    int e0 = offs_t[n], e1 = offs_t[n+1];
    float d2 = dv_t[n]*dv_t[n];
    float acc[8], v[8];
    ld8b(p.Gms + (size_t)n*256 + c, v);
    #pragma unroll
    for (int j = 0; j < 8; j++) acc[j] = d2 * v[j];
    for (int e = e0; e < e1; e++){
      int s = srcs_t[e] & (N-1);
      float nm = en_t[e];
      ld8b(p.Gms + (size_t)s*256 + c, v);
      #pragma unroll
      for (int j = 0; j < 8; j++) acc[j] += nm * v[j];
    }
    #pragma unroll
    for (int j = 0; j < 8; j++) sm.msh[nd*132 + c + j] = acc[j];
  }
  __syncthreads();
  float el = 0.f;
  {
    int d0 = l*4;
    #pragma unroll
    for (int q = 0; q < 4; q++){
      int d = d0 + q;
      size_t idx = (size_t)n*ZD + d;
      float mean = sm.msh[nd*132 + d] + ldI(p.enc_mean_b, d, f);
      float sd = splus(sm.msh[nd*132 + 64 + d] + ldI(p.enc_std_b, d, f));
      float zv = ldI(p.eps, (size_t)t*N*ZD + idx, f)*sd + mean;
      sm.zL[nd*68 + d] = zv;
      p.zbf[idx] = f2b(zv);
      stO(p.out, OUT_EM + (size_t)t*N*ZD + idx, mean, f);
      float pm = b2f(p.Gms[(size_t)n*256 + 128 + d]);
      float ps = splus(b2f(p.Gms[(size_t)n*256 + 192 + d]));
      stO(p.out, OUT_PM + (size_t)t*N*ZD + idx, pm, f);
      float s1 = sd + 1e-10f, s2 = ps + 1e-10f;
      float dm = mean - pm;
      el += 2.f*(logf(s2) - logf(s1)) - (s1*s1 + dm*dm)/(s2*s2) + 1.f;
    }
  }
  __syncthreads();
  // phi_z = relu(z @ phi_z_w + b) -> Tb2, LDS-staged weights
  {
    int c16 = l*16;
    float acc[16] = {};
    for (int k0 = 0; k0 < 64; k0 += 16){
      #pragma unroll
      for (int i = 0; i < 2; i++){
        int slot = tid + i*256;
        int kk = slot >> 5, cg = (slot & 31)*8;
        float w[8]; ldW8(p.phi_z_w, (size_t)(k0+kk)*HD + cg, f, w);
        *(uint4*)&sm.Wc[kk*264 + cg] = pack8(w);
      }
      __syncthreads();
      #pragma unroll
      for (int kk = 0; kk < 16; kk++){
        float zk = sm.zL[nd*68 + k0 + kk];
        float w[8];
        ld8b((const bf16*)&sm.Wc[kk*264 + c16], w);
        #pragma unroll
        for (int j = 0; j < 8; j++) acc[j] += zk*w[j];
        ld8b((const bf16*)&sm.Wc[kk*264 + c16 + 8], w);
        #pragma unroll
        for (int j = 0; j < 8; j++) acc[8+j] += zk*w[j];
      }
      __syncthreads();
    }
    float lo[8], hi[8];
    #pragma unroll
    for (int j = 0; j < 8; j++){
      lo[j] = fmaxf(acc[j]   + ldI(p.phi_z_b, c16 + j, f), 0.f);
      hi[j] = fmaxf(acc[8+j] + ldI(p.phi_z_b, c16 + 8 + j, f), 0.f);
    }
    *(uint4*)(p.Tb2 + (size_t)n*HD + c16)     = pack8(lo);
    *(uint4*)(p.Tb2 + (size_t)n*HD + c16 + 8) = pack8(hi);
  }
  sm.red[tid] = el; __syncthreads();
  for (int o = 128; o > 0; o >>= 1){ if (tid < o) sm.red[tid] += sm.red[tid+o]; __syncthreads(); }
  if (tid == 0) atomicAdd(p.scal + 4, sm.red[0] * (0.5f/((float)N*(float)ZD)));
}

// gru-x GEMM (0-767) + dec tiles (768-4863)
__global__ __launch_bounds__(256) void grux_dec_k(KP p, int t){   // grid 4864
  __shared__ SMem sm;
  int gb = blockIdx.x, tid = threadIdx.x, f = *p.dflag;
  if (gb < 768){
    const bf16* phiX = p.phiXa + (size_t)t*N*HD;
    int colblk = gb % 12, rowblk = gb / 12;
    int grp = colblk >> 2, c4 = colblk & 3;
    const void* W = (grp == 0) ? p.gxz : ((grp == 1) ? p.gxr : p.gxh);
    mfma_tile(sm, tid, f, phiX, 2, HD, p.Tb2, 2, HD, 256, 512,
              W, HD, c4*64, nullptr, 0, p.Gsx, 768, rowblk*64, colblk*64);
  } else {
    dec_tile1(p, sm, tid, t, gb - 768, f);
  }
}

// z gate + rh + hh projection (rh rows are block-local) -> z_g, Gh2.  grid 1024
__global__ __launch_bounds__(256) void zrhh_k(KP p, int t){
  __shared__ struct {
    short rhT[4*264];
    short Wc[32*264];
  } sm;
  int gb = blockIdx.x, tid = threadIdx.x, f = *p.dflag;
  const int* offs_t = p.offs + t*(N+1);
  const int* srcs_t = p.srcs + (size_t)t*E;
  const float* en_t = p.enorm + (size_t)t*E;
  const float* dv_t = p.dinv + t*N;
  int g4 = tid >> 6, lane = tid & 63;
  int n = gb*4 + g4, c = lane*8;
  {
    int e0 = offs_t[n], e1 = offs_t[n+1];
    float d2 = dv_t[n]*dv_t[n];
    float acc[8], v1[8], v2[8];
    ld8b(p.Gsx + (size_t)n*768 + c, v1);
    ld8b(p.Gs1 + 512 + (size_t)n*1024 + c, v2);
    #pragma unroll
    for (int j = 0; j < 8; j++) acc[j] = d2 * (v1[j] + v2[j]);
    for (int e = e0; e < e1; e++){
      int s = srcs_t[e] & (N-1);
      float nm = en_t[e];
      ld8b(p.Gsx + (size_t)s*768 + c, v1);
      ld8b(p.Gs1 + 512 + (size_t)s*1024 + c, v2);
      #pragma unroll
      for (int j = 0; j < 8; j++) acc[j] += nm * (v1[j] + v2[j]);
    }
    if (c < 256){
      size_t base = (size_t)n*HD + c;
      float4 o0, o1;
      o0.x = sigm(acc[0]); o0.y = sigm(acc[1]); o0.z = sigm(acc[2]); o0.w = sigm(acc[3]);
      o1.x = sigm(acc[4]); o1.y = sigm(acc[5]); o1.z = sigm(acc[6]); o1.w = sigm(acc[7]);
      *(float4*)(p.z_g + base) = o0;
      *(float4*)(p.z_g + base + 4) = o1;
    } else {
      size_t base = (size_t)n*HD + (c - 256);
      float r[8];
      #pragma unroll
      for (int j = 0; j < 8; j++) r[j] = sigm(acc[j]) * p.h_prev[base+j];
      *(uint4*)&sm.rhT[g4*264 + (c - 256)] = pack8(r);
    }
  }
  __syncthreads();
  // hh projection: Gh2[n] = rh[n] @ ghh   (4 nodes, 256 cols; 4 cols/thread)
  int nd = tid >> 6, c4 = (tid & 63)*4;
  float acc2[4] = {};
  for (int k0 = 0; k0 < 256; k0 += 32){
    #pragma unroll
    for (int i = 0; i < 4; i++){
      int slot = tid + i*256;
      int kk = slot >> 5, cg = (slot & 31)*8;
      float w[8]; ldW8(p.ghh, (size_t)(k0+kk)*HD + cg, f, w);
      *(uint4*)&sm.Wc[kk*264 + cg] = pack8(w);
    }
    __syncthreads();
    #pragma unroll 8
    for (int kk = 0; kk < 32; kk++){
      float a = s2f(sm.rhT[nd*264 + k0 + kk]);
      uint2 u = *(const uint2*)&sm.Wc[kk*264 + c4];
      acc2[0] += a*bits2f(u.x & 0xffffu);
      acc2[1] += a*bits2f(u.x >> 16);
      acc2[2] += a*bits2f(u.y & 0xffffu);
      acc2[3] += a*bits2f(u.y >> 16);
    }
    __syncthreads();
  }
  uint2 o; o.x = pack2(acc2[0],acc2[1]); o.y = pack2(acc2[2],acc2[3]);
  *(uint2*)(p.Gh2 + (size_t)(gb*4 + nd)*256 + c4) = o;
}

// h update (0-511); at t==3, block 512 finalizes kld/nll outputs
__global__ __launch_bounds__(256) void hagg_k(KP p, int t){
  int gb = blockIdx.x, tid = threadIdx.x, f = *p.dflag;
  if (gb >= 512){
    if (tid == 0){
      const float NNf = 16777216.f;
      float nll = 0.f;
      for (int tt = 0; tt < T_STEPS; tt++){
        float ts = p.scal[8+tt], P = p.scal[12+tt], Q = p.scal[16+tt];
        float posw = (NNf - ts)/ts;
        nll += (posw*P + Q) * 0.5f/(NNf - ts);
      }
      stO(p.out, 0, p.scal[4], f);
      stO(p.out, 1, nll, f);
    }
    return;
  }
  const int* offs_t = p.offs + t*(N+1);
  const int* srcs_t = p.srcs + (size_t)t*E;
  const float* en_t = p.enorm + (size_t)t*E;
  const float* dv_t = p.dinv + t*N;
  int g8 = tid >> 5, l = tid & 31;
  int n = gb*8 + g8, c = l*8;
  int e0 = offs_t[n], e1 = offs_t[n+1];
  float d2 = dv_t[n]*dv_t[n];
  float acc[8], v1[8], v2[8];
  ld8b(p.Gsx + 512 + (size_t)n*768 + c, v1);
  ld8b(p.Gh2 + (size_t)n*256 + c, v2);
  #pragma unroll
  for (int j = 0; j < 8; j++) acc[j] = d2 * (v1[j] + v2[j]);
  for (int e = e0; e < e1; e++){
    int s = srcs_t[e] & (N-1);
    float nm = en_t[e];
    ld8b(p.Gsx + 512 + (size_t)s*768 + c, v1);
    ld8b(p.Gh2 + (size_t)s*256 + c, v2);
    #pragma unroll
    for (int j = 0; j < 8; j++) acc[j] += nm * (v1[j] + v2[j]);
  }
  size_t base = (size_t)n*HD + c;
  #pragma unroll
  for (int j = 0; j < 8; j++){
    float z = p.z_g[base+j];
    float hv = p.h_prev[base+j];
    float nv = z*hv + (1.f - z)*tanhf(acc[j]);
    p.h_prev[base+j] = nv;
    p.h_bf[base+j] = f2b(nv);
    if (t == T_STEPS-1) stO(p.out, OUT_H + base + j, nv, f);
  }
}

// ---------------- host ----------------
extern "C" void kernel_launch(void* const* d_in, const int* in_sizes, int n_in,
                              void* d_out, int out_size, void* d_ws, size_t ws_size,
                              hipStream_t stream){
  KP P;
  P.x = d_in[0];  P.ei = (const int*)d_in[1];  P.adj = d_in[2];  P.eps = d_in[3];  P.h0 = d_in[4];
  P.phi_x_w = d_in[5];  P.phi_x_b = d_in[6];  P.phi_z_w = d_in[7];  P.phi_z_b = d_in[8];
  P.enc_w = d_in[9];  P.enc_b = d_in[10];
  P.enc_mean_w = d_in[11];  P.enc_mean_b = d_in[12];
  P.enc_std_w = d_in[13];   P.enc_std_b = d_in[14];
  P.prior_w = d_in[15];  P.prior_b = d_in[16];
  P.prior_mean_w = d_in[17];  P.prior_mean_b = d_in[18];
  P.prior_std_w = d_in[19];   P.prior_std_b = d_in[20];
  P.gxz = d_in[21];  P.ghz = d_in[22];  P.gxr = d_in[23];
  P.ghr = d_in[24];  P.gxh = d_in[25];  P.ghh = d_in[26];
  P.out = d_out;

  char* wp = (char*)d_ws;
  auto alloc = [&](size_t bytes){ void* q = (void*)wp; wp += (bytes + 255) & ~(size_t)255; return q; };
  P.scal  = (float*)alloc(64*sizeof(float));
  P.dflag = (int*)  alloc(256);
  P.dinv  = (float*)alloc((size_t)T_STEPS*N*4);
  P.offs  = (int*)  alloc((size_t)T_STEPS*(N+1)*4);
  P.srcs  = (int*)  alloc((size_t)T_STEPS*E*4);
  P.enorm = (float*)alloc((size_t)T_STEPS*E*4);
  P.deg   = (int*)  alloc((size_t)T_STEPS*N*4);
  P.h_prev= (float*)alloc((size_t)N*HD*4);
  P.h_bf  = (bf16*) alloc((size_t)N*HD*2);
  P.phiXa = (bf16*) alloc((size_t)T_STEPS*N*HD*2);
  P.Tb2   = (bf16*) alloc((size_t)N*HD*2);
  P.zbf   = (bf16*) alloc((size_t)N*ZD*2);
  P.z_g   = (float*)alloc((size_t)N*HD*4);
  P.Gs1   = (bf16*) alloc((size_t)N*1024*2);
  P.Gsx   = (bf16*) alloc((size_t)N*768*2);
  P.Gms   = (bf16*) alloc((size_t)N*256*2);
  P.Gh2   = (bf16*) alloc((size_t)N*256*2);

  setup0_k<<<66,256,0,stream>>>(P);
  count_deg_k<<<1024,256,0,stream>>>(P);
  setup2_k<<<1060,256,0,stream>>>(P);
  scatter_k<<<1024,256,0,stream>>>(P);
  for (int t = 0; t < T_STEPS; t++){
    g1_k<<<1024,256,0,stream>>>(P, t);
    encagg_k<<<512,256,0,stream>>>(P, t);
    msaggpost_k<<<256,256,0,stream>>>(P, t);
    grux_dec_k<<<4864,256,0,stream>>>(P, t);
    zrhh_k<<<1024,256,0,stream>>>(P, t);
    hagg_k<<<(t == T_STEPS-1) ? 513 : 512,256,0,stream>>>(P, t);
  }
}

// Round 12
// 1404.242 us; speedup vs baseline: 1.4819x; 1.1846x over previous
//
#include <hip/hip_runtime.h>
#include <hip/hip_bf16.h>

#define T_STEPS 4
#define N 4096
#define E 65536
#define XD 256
#define HD 256
#define ZD 64

typedef __hip_bfloat16 bf16;
typedef __attribute__((ext_vector_type(8))) short short8;
typedef __attribute__((ext_vector_type(4))) float f32x4;

__device__ __forceinline__ float b2f(bf16 v){ return __bfloat162float(v); }
__device__ __forceinline__ bf16 f2b(float v){ return __float2bfloat16(v); }
__device__ __forceinline__ short f2s(float v){ return __builtin_bit_cast(short, f2b(v)); }
__device__ __forceinline__ float bits2f(unsigned int s){ return __builtin_bit_cast(float, s << 16); }
__device__ __forceinline__ float s2f(short s){ return bits2f((unsigned int)(unsigned short)s); }
// fast transcendentals (HW exp2/log2 based; ~1e-6 rel err — far under the 6e-2 threshold)
__device__ __forceinline__ float splus(float x){ return (x > 15.f) ? x : __logf(1.f + __expf(x)); }
__device__ __forceinline__ float sigm(float x){ return 1.f/(1.f + __expf(-x)); }
__device__ __forceinline__ float ftanh(float x){ return 2.f/(1.f + __expf(-2.f*x)) - 1.f; }

__device__ __forceinline__ float ldI(const void* p, size_t i, int f){
  return f ? ((const float*)p)[i] : b2f(((const bf16*)p)[i]);
}
__device__ __forceinline__ void stO(void* p, size_t i, float v, int f){
  if (f) ((float*)p)[i] = v; else ((bf16*)p)[i] = f2b(v);
}
__device__ __forceinline__ void ld8b(const bf16* p, float v[8]){
  uint4 u = *(const uint4*)p;
  v[0]=bits2f(u.x & 0xffffu); v[1]=bits2f(u.x >> 16);
  v[2]=bits2f(u.y & 0xffffu); v[3]=bits2f(u.y >> 16);
  v[4]=bits2f(u.z & 0xffffu); v[5]=bits2f(u.z >> 16);
  v[6]=bits2f(u.w & 0xffffu); v[7]=bits2f(u.w >> 16);
}
__device__ __forceinline__ void ldW8(const void* W, size_t off, int f, float w[8]){
  if (f == 0){ ld8b((const bf16*)W + off, w); }
  else {
    const float* Wf = (const float*)W + off;
    float4 a = *(const float4*)Wf, b = *(const float4*)(Wf + 4);
    w[0]=a.x; w[1]=a.y; w[2]=a.z; w[3]=a.w; w[4]=b.x; w[5]=b.y; w[6]=b.z; w[7]=b.w;
  }
}
__device__ __forceinline__ unsigned int pack2(float a, float b){
  return (unsigned int)(unsigned short)__builtin_bit_cast(unsigned short, f2b(a))
       | ((unsigned int)(unsigned short)__builtin_bit_cast(unsigned short, f2b(b)) << 16);
}
__device__ __forceinline__ uint4 pack8(const float v[8]){
  uint4 o; o.x = pack2(v[0],v[1]); o.y = pack2(v[2],v[3]);
  o.z = pack2(v[4],v[5]); o.w = pack2(v[6],v[7]);
  return o;
}

union SMem {
  struct { short As[64*40]; short Wt[64*40]; } g;                        // 10.2 KB (GEMM)
  struct { short Zi[64*72]; short Zj[64*72]; short Adj[64*72];
           float redA[256]; float redB[256]; float redC[256]; } z;       // 30.7 KB (dec)
  struct { float msh[16*132]; } m;                                       // 8.4 KB
  int sh[256];
  float red[256];
};

struct KP {
  const void *x, *adj, *eps, *h0;
  const int* ei;
  const void *phi_x_w, *phi_x_b, *phi_z_w, *phi_z_b;
  const void *enc_w, *enc_b, *enc_mean_w, *enc_mean_b, *enc_std_w, *enc_std_b;
  const void *prior_w, *prior_b, *prior_mean_w, *prior_mean_b, *prior_std_w, *prior_std_b;
  const void *gxz, *ghz, *gxr, *ghr, *gxh, *ghh;
  void* out;
  float* scal; int* dflag; float* dinv; int* offs; int* srcs; float* enorm; int* deg;
  float* h_prev; bf16* h_bf; bf16* phiXa; bf16* Tb1; bf16* Tb2;
  bf16* zbf; float* z_g; bf16* Gs1; bf16* Gsx; bf16* Gms; bf16* Gh2;
};

#define OUT_EM ((size_t)2)
#define OUT_PM ((size_t)(2 + (size_t)T_STEPS*N*ZD))
#define OUT_H  ((size_t)(2 + (size_t)2*T_STEPS*N*ZD))

// ---------------- MFMA 64x64 tile: C = [A1|A2] @ W(+bias)(+relu), bf16 out ----------------
__device__ void mfma_tile(SMem& sm, int tid, int f,
    const void* A1, int am1, int lda1, const void* A2, int am2, int lda2,
    int K1, int K, const void* W, int ldw, int wcol,
    const void* bias, int act, bf16* C, int ldc, int row0, int ccol0){
  int ar = tid >> 2, akk = (tid & 3)*8;
  int wk = tid >> 3, wn = (tid & 7)*8;
  int wave = tid >> 6, lane = tid & 63, m = lane & 15, kq = lane >> 4;
  f32x4 acc[4] = {};
  for (int k0 = 0; k0 < K; k0 += 32){
    const void* A; int am, lda, kb;
    if (k0 < K1){ A = A1; am = am1; lda = lda1; kb = k0; }
    else        { A = A2; am = am2; lda = lda2; kb = k0 - K1; }
    size_t aidx = (size_t)(row0 + ar)*lda + kb + akk;
    short8 av;
    if (am == 2 || (am == 1 && f == 0)){
      av = *(const short8*)((const short*)A + aidx);
    } else {
      const float* Af = (const float*)A;
      float4 u0 = *(const float4*)(Af + aidx);
      float4 u1 = *(const float4*)(Af + aidx + 4);
      av[0]=f2s(u0.x); av[1]=f2s(u0.y); av[2]=f2s(u0.z); av[3]=f2s(u0.w);
      av[4]=f2s(u1.x); av[5]=f2s(u1.y); av[6]=f2s(u1.z); av[7]=f2s(u1.w);
    }
    *(short8*)&sm.g.As[ar*40 + akk] = av;
    size_t wi = (size_t)(k0 + wk)*ldw + wcol + wn;
    float wf[8]; short wv[8];
    if (f == 0){
      short8 t8 = *(const short8*)((const short*)W + wi);
      #pragma unroll
      for (int j = 0; j < 8; j++) wv[j] = t8[j];
    } else {
      ldW8(W, wi, f, wf);
      #pragma unroll
      for (int j = 0; j < 8; j++) wv[j] = f2s(wf[j]);
    }
    #pragma unroll
    for (int j = 0; j < 8; j++){
      int nrow = wn + j;
      int col = (((wk >> 3) ^ ((nrow >> 3) & 3)) << 3) | (wk & 7);
      sm.g.Wt[nrow*40 + col] = wv[j];
    }
    __syncthreads();
    short8 afr = *(const short8*)&sm.g.As[(wave*16 + m)*40 + kq*8];
    #pragma unroll
    for (int t4 = 0; t4 < 4; t4++){
      int nb = t4*16 + m;
      short8 bfr = *(const short8*)&sm.g.Wt[nb*40 + ((kq ^ ((nb >> 3) & 3)) << 3)];
      acc[t4] = __builtin_amdgcn_mfma_f32_16x16x32_bf16(afr, bfr, acc[t4], 0, 0, 0);
    }
    __syncthreads();
  }
  #pragma unroll
  for (int t4 = 0; t4 < 4; t4++){
    int c = ccol0 + t4*16 + m;
    float bv = bias ? ldI(bias, wcol + t4*16 + m, f) : 0.f;
    #pragma unroll
    for (int reg = 0; reg < 4; reg++){
      int r = row0 + wave*16 + kq*4 + reg;
      float v = acc[t4][reg] + bv;
      if (act == 1) v = fmaxf(v, 0.f);
      C[(size_t)r*ldc + c] = f2b(v);
    }
  }
}

// ---------------- dec 64x64 tile via MFMA, adj through LDS, fused 3-way reduce ------------
__device__ void dec_tile1(const KP& p, SMem& sm, int tid, int t, int u, int f){
  int i0 = (u >> 6)*64, j0 = (u & 63)*64;
  size_t aoff = (size_t)t*N*N;
  #pragma unroll
  for (int i = 0; i < 2; i++){
    int idx = tid + i*256;
    int r = idx >> 3, c = idx & 7;
    int col = ((c ^ ((r >> 3) & 3)) << 3);
    *(short8*)&sm.z.Zi[r*72 + col] = *(const short8*)((const short*)p.zbf + (size_t)(i0+r)*ZD + c*8);
    *(short8*)&sm.z.Zj[r*72 + col] = *(const short8*)((const short*)p.zbf + (size_t)(j0+r)*ZD + c*8);
  }
  {
    int row = tid >> 2, c0 = (tid & 3)*16;
    if (f){
      const float* ap = (const float*)p.adj + aoff + (size_t)(i0+row)*N + j0 + c0;
      short tmp[16];
      #pragma unroll
      for (int q = 0; q < 16; q += 4){
        float4 v = *(const float4*)(ap + q);
        tmp[q]=f2s(v.x); tmp[q+1]=f2s(v.y); tmp[q+2]=f2s(v.z); tmp[q+3]=f2s(v.w);
      }
      *(short8*)&sm.z.Adj[row*72 + c0]     = *(short8*)&tmp[0];
      *(short8*)&sm.z.Adj[row*72 + c0 + 8] = *(short8*)&tmp[8];
    } else {
      const short* ap = (const short*)p.adj + aoff + (size_t)(i0+row)*N + j0 + c0;
      *(short8*)&sm.z.Adj[row*72 + c0]     = *(const short8*)ap;
      *(short8*)&sm.z.Adj[row*72 + c0 + 8] = *(const short8*)(ap + 8);
    }
  }
  __syncthreads();
  int wave = tid >> 6, lane = tid & 63, m = lane & 15, kq = lane >> 4;
  int ra = wave*16 + m, sa = (ra >> 3) & 3;
  short8 a1 = *(const short8*)&sm.z.Zi[ra*72 + ((kq ^ sa) << 3)];
  short8 a2 = *(const short8*)&sm.z.Zi[ra*72 + (((kq+4) ^ sa) << 3)];
  f32x4 acc[4] = {};
  #pragma unroll
  for (int t4 = 0; t4 < 4; t4++){
    int rb = t4*16 + m, sb2 = (rb >> 3) & 3;
    short8 b1 = *(const short8*)&sm.z.Zj[rb*72 + ((kq ^ sb2) << 3)];
    short8 b2 = *(const short8*)&sm.z.Zj[rb*72 + (((kq+4) ^ sb2) << 3)];
    acc[t4] = __builtin_amdgcn_mfma_f32_16x16x32_bf16(a1, b1, acc[t4], 0, 0, 0);
    acc[t4] = __builtin_amdgcn_mfma_f32_16x16x32_bf16(a2, b2, acc[t4], 0, 0, 0);
  }
  float lts = 0.f, lP = 0.f, lQ = 0.f;
  #pragma unroll
  for (int t4 = 0; t4 < 4; t4++){
    int lj = t4*16 + m;
    #pragma unroll
    for (int reg = 0; reg < 4; reg++){
      int li = wave*16 + kq*4 + reg;
      float av = s2f(sm.z.Adj[li*72 + lj]);
      float dec = sigm(acc[t4][reg]);
      lts += av;
      lQ += (1.f - av)*splus(dec);
      if (av != 0.f) lP += av*splus(-dec);
    }
  }
  __syncthreads();
  sm.z.redA[tid] = lts; sm.z.redB[tid] = lP; sm.z.redC[tid] = lQ;
  __syncthreads();
  for (int o = 128; o > 0; o >>= 1){
    if (tid < o){
      sm.z.redA[tid] += sm.z.redA[tid+o];
      sm.z.redB[tid] += sm.z.redB[tid+o];
      sm.z.redC[tid] += sm.z.redC[tid+o];
    }
    __syncthreads();
  }
  if (tid == 0){
    atomicAdd(p.scal + 8 + t,  sm.z.redA[0]);
    atomicAdd(p.scal + 12 + t, sm.z.redB[0]);
    atomicAdd(p.scal + 16 + t, sm.z.redC[0]);
  }
}

// ---------------- setup kernels ----------------
__global__ __launch_bounds__(256) void setup0_k(KP p){
  int gb = blockIdx.x, tid = threadIdx.x;
  if (gb == 0){ if (tid < 64) p.scal[tid] = 0.f; }
  else if (gb == 1){
    if (tid == 0){
      const unsigned short* u = (const unsigned short*)p.x;
      int big = 0;
      for (int i = 0; i < 256; i++){ int e = (u[i] >> 7) & 0xFF; if (e >= 134) big++; }
      *p.dflag = (big > 16) ? 1 : 0;
    }
  } else {
    p.deg[(gb-2)*256 + tid] = 0;
  }
}

__global__ __launch_bounds__(256) void count_deg_k(KP p){
  int idx = blockIdx.x*256 + threadIdx.x;
  int t = idx >> 16, e = idx & (E-1);
  int dst = p.ei[(size_t)t*2*E + E + e] & (N-1);
  atomicAdd(&p.deg[t*N + dst], 1);
}

// scan+cursor (0-3) + h0 copy (4-35) + phi_x GEMM (36-1059)
__global__ __launch_bounds__(256) void setup2_k(KP p){
  __shared__ SMem sm;
  int gb = blockIdx.x, tid = threadIdx.x;
  int f = *p.dflag;
  if (gb < 4){
    int t = gb;
    const int* dg = p.deg + t*N;
    int* of = p.offs + t*(N+1);
    int base = tid*16;
    int loc[16]; int s = 0;
    #pragma unroll
    for (int i = 0; i < 16; i++){ loc[i] = s; s += dg[base+i]; }
    sm.sh[tid] = s;
    __syncthreads();
    for (int o = 1; o < 256; o <<= 1){
      int v = (tid >= o) ? sm.sh[tid-o] : 0;
      __syncthreads();
      sm.sh[tid] += v;
      __syncthreads();
    }
    int pre = (tid == 0) ? 0 : sm.sh[tid-1];
    #pragma unroll
    for (int i = 0; i < 16; i++){
      int deg_i = dg[base+i];
      of[base+i] = pre + loc[i];
      p.dinv[t*N + base + i] = rsqrtf(1.f + (float)deg_i);
    }
    if (tid == 255) of[N] = sm.sh[255];
    __syncthreads();
    #pragma unroll
    for (int i = 0; i < 16; i++) p.deg[t*N + base + i] = pre + loc[i];  // cursor
  } else if (gb < 36){
    for (int idx = (gb-4)*256 + tid; idx < N*HD; idx += 32*256){
      float v = ldI(p.h0, idx, f);
      p.h_prev[idx] = v; p.h_bf[idx] = f2b(v);
    }
  } else {
    int u = gb - 36;
    int colblk = u & 3, rowblk = u >> 2;
    mfma_tile(sm, tid, f, p.x, 1, XD, nullptr, 0, 0, XD, XD,
              p.phi_x_w, HD, colblk*64, p.phi_x_b, 1,
              p.phiXa, HD, rowblk*64, colblk*64);
  }
}

// ---------------- step kernels ----------------
// g1: GEMM tiles (0-1023); at t==0, blocks 1024-2047 perform the edge scatter
// (both halves depend only on setup2; same-dispatch completion precedes encagg)
__global__ __launch_bounds__(256) void g1_k(KP p, int t){
  __shared__ SMem sm;
  int gb = blockIdx.x, tid = threadIdx.x, f = *p.dflag;
  if (gb >= 1024){
    int idx = (gb - 1024)*256 + tid;      // T*E total
    int tt = idx >> 16, e = idx & (E-1);
    int s = p.ei[(size_t)tt*2*E + e] & (N-1);
    int d = p.ei[(size_t)tt*2*E + E + e] & (N-1);
    int pos = atomicAdd(&p.deg[tt*N + d], 1);
    if (pos >= 0 && pos < E){
      p.srcs[(size_t)tt*E + pos] = s;
      p.enorm[(size_t)tt*E + pos] = p.dinv[tt*N + s] * p.dinv[tt*N + d];
    }
    return;
  }
  const bf16* phiX = p.phiXa + (size_t)t*N*HD;
  int colblk = gb & 15, rowblk = gb >> 4;
  int grp = colblk >> 2, c4 = colblk & 3;
  if (grp == 0)
    mfma_tile(sm, tid, f, phiX, 2, HD, p.h_bf, 2, HD, 256, 512,
              p.enc_w, HD, c4*64, nullptr, 0, p.Gs1, 1024, rowblk*64, colblk*64);
  else if (grp == 1)
    mfma_tile(sm, tid, f, p.h_bf, 2, HD, nullptr, 0, 0, 256, 256,
              p.prior_w, HD, c4*64, p.prior_b, 1, p.Gs1, 1024, rowblk*64, colblk*64);
  else if (grp == 2)
    mfma_tile(sm, tid, f, p.h_bf, 2, HD, nullptr, 0, 0, 256, 256,
              p.ghz, HD, c4*64, nullptr, 0, p.Gs1, 1024, rowblk*64, colblk*64);
  else
    mfma_tile(sm, tid, f, p.h_bf, 2, HD, nullptr, 0, 0, 256, 256,
              p.ghr, HD, c4*64, nullptr, 0, p.Gs1, 1024, rowblk*64, colblk*64);
}

__global__ __launch_bounds__(256) void encagg_pms_k(KP p, int t){   // grid 640
  __shared__ SMem sm;
  int gb = blockIdx.x, tid = threadIdx.x, f = *p.dflag;
  const int* offs_t = p.offs + t*(N+1);
  const int* srcs_t = p.srcs + (size_t)t*E;
  const float* en_t = p.enorm + (size_t)t*E;
  const float* dv_t = p.dinv + t*N;
  if (gb < 512){
    int g8 = tid >> 5, l = tid & 31;
    int n = gb*8 + g8, c = l*8;
    int e0 = offs_t[n], e1 = offs_t[n+1];
    float d2 = dv_t[n]*dv_t[n];
    float acc[8], va[8], vb[8];
    ld8b(p.Gs1 + (size_t)n*1024 + c, va);
    #pragma unroll
    for (int j = 0; j < 8; j++) acc[j] = d2 * va[j];
    int e = e0;
    for (; e + 1 < e1; e += 2){
      int s0 = srcs_t[e] & (N-1), s1 = srcs_t[e+1] & (N-1);
      float n0 = en_t[e], n1 = en_t[e+1];
      ld8b(p.Gs1 + (size_t)s0*1024 + c, va);
      ld8b(p.Gs1 + (size_t)s1*1024 + c, vb);
      #pragma unroll
      for (int j = 0; j < 8; j++) acc[j] += n0*va[j] + n1*vb[j];
    }
    if (e < e1){
      int s0 = srcs_t[e] & (N-1);
      float n0 = en_t[e];
      ld8b(p.Gs1 + (size_t)s0*1024 + c, va);
      #pragma unroll
      for (int j = 0; j < 8; j++) acc[j] += n0*va[j];
    }
    #pragma unroll
    for (int j = 0; j < 8; j++) acc[j] = fmaxf(acc[j] + ldI(p.enc_b, c + j, f), 0.f);
    *(uint4*)(p.Tb1 + (size_t)n*HD + c) = pack8(acc);
  } else {
    int u = gb - 512;
    int colblk = u & 1, rowblk = u >> 1;
    mfma_tile(sm, tid, f, p.Gs1 + 256, 2, 1024, nullptr, 0, 0, 256, 256,
              colblk ? p.prior_std_w : p.prior_mean_w, ZD, 0,
              colblk ? p.prior_std_b : p.prior_mean_b, 0,
              p.Gms, 256, rowblk*64, 128 + colblk*64);
  }
}

__global__ __launch_bounds__(256) void encms_k(KP p, int t){   // grid 128
  __shared__ SMem sm;
  int gb = blockIdx.x, tid = threadIdx.x, f = *p.dflag;
  int colblk = gb & 1, rowblk = gb >> 1;
  mfma_tile(sm, tid, f, p.Tb1, 2, HD, nullptr, 0, 0, 256, 256,
            colblk ? p.enc_std_w : p.enc_mean_w, ZD, 0, nullptr, 0,
            p.Gms, 256, rowblk*64, colblk*64);
}

// fused: enc mean/std aggregation + reparam + outputs + kld (grid 256)
__global__ __launch_bounds__(256) void msaggpost_k(KP p, int t){
  __shared__ SMem sm;
  int gb = blockIdx.x, tid = threadIdx.x, f = *p.dflag;
  const int* offs_t = p.offs + t*(N+1);
  const int* srcs_t = p.srcs + (size_t)t*E;
  const float* en_t = p.enorm + (size_t)t*E;
  const float* dv_t = p.dinv + t*N;
  int g16 = tid >> 4, l = tid & 15;
  int n = gb*16 + g16, c = l*8;
  {
    int e0 = offs_t[n], e1 = offs_t[n+1];
    float d2 = dv_t[n]*dv_t[n];
    float acc[8], va[8], vb[8];
    ld8b(p.Gms + (size_t)n*256 + c, va);
    #pragma unroll
    for (int j = 0; j < 8; j++) acc[j] = d2 * va[j];
    int e = e0;
    for (; e + 1 < e1; e += 2){
      int s0 = srcs_t[e] & (N-1), s1 = srcs_t[e+1] & (N-1);
      float n0 = en_t[e], n1 = en_t[e+1];
      ld8b(p.Gms + (size_t)s0*256 + c, va);
      ld8b(p.Gms + (size_t)s1*256 + c, vb);
      #pragma unroll
      for (int j = 0; j < 8; j++) acc[j] += n0*va[j] + n1*vb[j];
    }
    if (e < e1){
      int s0 = srcs_t[e] & (N-1);
      float n0 = en_t[e];
      ld8b(p.Gms + (size_t)s0*256 + c, va);
      #pragma unroll
      for (int j = 0; j < 8; j++) acc[j] += n0*va[j];
    }
    #pragma unroll
    for (int j = 0; j < 8; j++) sm.m.msh[g16*132 + c + j] = acc[j];
  }
  __syncthreads();
  float el = 0.f;
  {
    int d0 = l*4;
    #pragma unroll
    for (int q = 0; q < 4; q++){
      int d = d0 + q;
      size_t idx = (size_t)n*ZD + d;
      float mean = sm.m.msh[g16*132 + d] + ldI(p.enc_mean_b, d, f);
      float sd = splus(sm.m.msh[g16*132 + 64 + d] + ldI(p.enc_std_b, d, f));
      float zv = ldI(p.eps, (size_t)t*N*ZD + idx, f)*sd + mean;
      p.zbf[idx] = f2b(zv);
      stO(p.out, OUT_EM + (size_t)t*N*ZD + idx, mean, f);
      float pm = b2f(p.Gms[(size_t)n*256 + 128 + d]);
      float ps = splus(b2f(p.Gms[(size_t)n*256 + 192 + d]));
      stO(p.out, OUT_PM + (size_t)t*N*ZD + idx, pm, f);
      float s1 = sd + 1e-10f, s2 = ps + 1e-10f;
      float dm = mean - pm;
      el += 2.f*(__logf(s2) - __logf(s1)) - (s1*s1 + dm*dm)/(s2*s2) + 1.f;
    }
  }
  __syncthreads();
  sm.red[tid] = el; __syncthreads();
  for (int o = 128; o > 0; o >>= 1){ if (tid < o) sm.red[tid] += sm.red[tid+o]; __syncthreads(); }
  if (tid == 0) atomicAdd(p.scal + 4, sm.red[0] * (0.5f/((float)N*(float)ZD)));
}

__global__ __launch_bounds__(256) void phiz_k(KP p, int t){   // grid 256
  __shared__ SMem sm;
  int gb = blockIdx.x, tid = threadIdx.x, f = *p.dflag;
  int colblk = gb & 3, rowblk = gb >> 2;
  mfma_tile(sm, tid, f, p.zbf, 2, ZD, nullptr, 0, 0, ZD, ZD,
            p.phi_z_w, HD, colblk*64, p.phi_z_b, 1, p.Tb2, HD, rowblk*64, colblk*64);
}

// gru-x GEMM (0-767) + dec tiles, one per block (768-4863)
__global__ __launch_bounds__(256) void grux_dec_k(KP p, int t){   // grid 4864
  __shared__ SMem sm;
  int gb = blockIdx.x, tid = threadIdx.x, f = *p.dflag;
  if (gb < 768){
    const bf16* phiX = p.phiXa + (size_t)t*N*HD;
    int colblk = gb % 12, rowblk = gb / 12;
    int grp = colblk >> 2, c4 = colblk & 3;
    const void* W = (grp == 0) ? p.gxz : ((grp == 1) ? p.gxr : p.gxh);
    mfma_tile(sm, tid, f, phiX, 2, HD, p.Tb2, 2, HD, 256, 512,
              W, HD, c4*64, nullptr, 0, p.Gsx, 768, rowblk*64, colblk*64);
  } else {
    dec_tile1(p, sm, tid, t, gb - 768, f);
  }
}

__global__ __launch_bounds__(256) void zr_k(KP p, int t){   // grid 1024
  int gb = blockIdx.x, tid = threadIdx.x;
  const int* offs_t = p.offs + t*(N+1);
  const int* srcs_t = p.srcs + (size_t)t*E;
  const float* en_t = p.enorm + (size_t)t*E;
  const float* dv_t = p.dinv + t*N;
  int g4 = tid >> 6, lane = tid & 63;
  int n = gb*4 + g4, c = lane*8;
  int e0 = offs_t[n], e1 = offs_t[n+1];
  float d2 = dv_t[n]*dv_t[n];
  float acc[8], v1[8], v2[8], v3[8], v4[8];
  ld8b(p.Gsx + (size_t)n*768 + c, v1);
  ld8b(p.Gs1 + 512 + (size_t)n*1024 + c, v2);
  #pragma unroll
  for (int j = 0; j < 8; j++) acc[j] = d2 * (v1[j] + v2[j]);
  int e = e0;
  for (; e + 1 < e1; e += 2){
    int s0 = srcs_t[e] & (N-1), s1 = srcs_t[e+1] & (N-1);
    float n0 = en_t[e], n1 = en_t[e+1];
    ld8b(p.Gsx + (size_t)s0*768 + c, v1);
    ld8b(p.Gs1 + 512 + (size_t)s0*1024 + c, v2);
    ld8b(p.Gsx + (size_t)s1*768 + c, v3);
    ld8b(p.Gs1 + 512 + (size_t)s1*1024 + c, v4);
    #pragma unroll
    for (int j = 0; j < 8; j++) acc[j] += n0*(v1[j] + v2[j]) + n1*(v3[j] + v4[j]);
  }
  if (e < e1){
    int s0 = srcs_t[e] & (N-1);
    float n0 = en_t[e];
    ld8b(p.Gsx + (size_t)s0*768 + c, v1);
    ld8b(p.Gs1 + 512 + (size_t)s0*1024 + c, v2);
    #pragma unroll
    for (int j = 0; j < 8; j++) acc[j] += n0*(v1[j] + v2[j]);
  }
  if (c < 256){
    size_t base = (size_t)n*HD + c;
    float4 o0, o1;
    o0.x = sigm(acc[0]); o0.y = sigm(acc[1]); o0.z = sigm(acc[2]); o0.w = sigm(acc[3]);
    o1.x = sigm(acc[4]); o1.y = sigm(acc[5]); o1.z = sigm(acc[6]); o1.w = sigm(acc[7]);
    *(float4*)(p.z_g + base) = o0;
    *(float4*)(p.z_g + base + 4) = o1;
  } else {
    size_t base = (size_t)n*HD + (c - 256);
    float r[8];
    #pragma unroll
    for (int j = 0; j < 8; j++) r[j] = sigm(acc[j]) * p.h_prev[base+j];
    *(uint4*)(p.Tb1 + base) = pack8(r);
  }
}

__global__ __launch_bounds__(256) void hh_k(KP p, int t){   // grid 256
  __shared__ SMem sm;
  int gb = blockIdx.x, tid = threadIdx.x, f = *p.dflag;
  int colblk = gb & 3, rowblk = gb >> 2;
  mfma_tile(sm, tid, f, p.Tb1, 2, HD, nullptr, 0, 0, 256, 256,
            p.ghh, HD, colblk*64, nullptr, 0, p.Gh2, 256, rowblk*64, colblk*64);
}

// h update (0-511); at t==3, block 512 finalizes kld/nll outputs
__global__ __launch_bounds__(256) void hagg_k(KP p, int t){
  int gb = blockIdx.x, tid = threadIdx.x, f = *p.dflag;
  if (gb >= 512){
    if (tid == 0){
      const float NNf = 16777216.f;
      float nll = 0.f;
      for (int tt = 0; tt < T_STEPS; tt++){
        float ts = p.scal[8+tt], P = p.scal[12+tt], Q = p.scal[16+tt];
        float posw = (NNf - ts)/ts;
        nll += (posw*P + Q) * 0.5f/(NNf - ts);
      }
      stO(p.out, 0, p.scal[4], f);
      stO(p.out, 1, nll, f);
    }
    return;
  }
  const int* offs_t = p.offs + t*(N+1);
  const int* srcs_t = p.srcs + (size_t)t*E;
  const float* en_t = p.enorm + (size_t)t*E;
  const float* dv_t = p.dinv + t*N;
  int g8 = tid >> 5, l = tid & 31;
  int n = gb*8 + g8, c = l*8;
  int e0 = offs_t[n], e1 = offs_t[n+1];
  float d2 = dv_t[n]*dv_t[n];
  float acc[8], v1[8], v2[8], v3[8], v4[8];
  ld8b(p.Gsx + 512 + (size_t)n*768 + c, v1);
  ld8b(p.Gh2 + (size_t)n*256 + c, v2);
  #pragma unroll
  for (int j = 0; j < 8; j++) acc[j] = d2 * (v1[j] + v2[j]);
  int e = e0;
  for (; e + 1 < e1; e += 2){
    int s0 = srcs_t[e] & (N-1), s1 = srcs_t[e+1] & (N-1);
    float n0 = en_t[e], n1 = en_t[e+1];
    ld8b(p.Gsx + 512 + (size_t)s0*768 + c, v1);
    ld8b(p.Gh2 + (size_t)s0*256 + c, v2);
    ld8b(p.Gsx + 512 + (size_t)s1*768 + c, v3);
    ld8b(p.Gh2 + (size_t)s1*256 + c, v4);
    #pragma unroll
    for (int j = 0; j < 8; j++) acc[j] += n0*(v1[j] + v2[j]) + n1*(v3[j] + v4[j]);
  }
  if (e < e1){
    int s0 = srcs_t[e] & (N-1);
    float n0 = en_t[e];
    ld8b(p.Gsx + 512 + (size_t)s0*768 + c, v1);
    ld8b(p.Gh2 + (size_t)s0*256 + c, v2);
    #pragma unroll
    for (int j = 0; j < 8; j++) acc[j] += n0*(v1[j] + v2[j]);
  }
  size_t base = (size_t)n*HD + c;
  #pragma unroll
  for (int j = 0; j < 8; j++){
    float z = p.z_g[base+j];
    float hv = p.h_prev[base+j];
    float nv = z*hv + (1.f - z)*ftanh(acc[j]);
    p.h_prev[base+j] = nv;
    p.h_bf[base+j] = f2b(nv);
    if (t == T_STEPS-1) stO(p.out, OUT_H + base + j, nv, f);
  }
}

// ---------------- host ----------------
extern "C" void kernel_launch(void* const* d_in, const int* in_sizes, int n_in,
                              void* d_out, int out_size, void* d_ws, size_t ws_size,
                              hipStream_t stream){
  KP P;
  P.x = d_in[0];  P.ei = (const int*)d_in[1];  P.adj = d_in[2];  P.eps = d_in[3];  P.h0 = d_in[4];
  P.phi_x_w = d_in[5];  P.phi_x_b = d_in[6];  P.phi_z_w = d_in[7];  P.phi_z_b = d_in[8];
  P.enc_w = d_in[9];  P.enc_b = d_in[10];
  P.enc_mean_w = d_in[11];  P.enc_mean_b = d_in[12];
  P.enc_std_w = d_in[13];   P.enc_std_b = d_in[14];
  P.prior_w = d_in[15];  P.prior_b = d_in[16];
  P.prior_mean_w = d_in[17];  P.prior_mean_b = d_in[18];
  P.prior_std_w = d_in[19];   P.prior_std_b = d_in[20];
  P.gxz = d_in[21];  P.ghz = d_in[22];  P.gxr = d_in[23];
  P.ghr = d_in[24];  P.gxh = d_in[25];  P.ghh = d_in[26];
  P.out = d_out;

  char* wp = (char*)d_ws;
  auto alloc = [&](size_t bytes){ void* q = (void*)wp; wp += (bytes + 255) & ~(size_t)255; return q; };
  P.scal  = (float*)alloc(64*sizeof(float));
  P.dflag = (int*)  alloc(256);
  P.dinv  = (float*)alloc((size_t)T_STEPS*N*4);
  P.offs  = (int*)  alloc((size_t)T_STEPS*(N+1)*4);
  P.srcs  = (int*)  alloc((size_t)T_STEPS*E*4);
  P.enorm = (float*)alloc((size_t)T_STEPS*E*4);
  P.deg   = (int*)  alloc((size_t)T_STEPS*N*4);
  P.h_prev= (float*)alloc((size_t)N*HD*4);
  P.h_bf  = (bf16*) alloc((size_t)N*HD*2);
  P.phiXa = (bf16*) alloc((size_t)T_STEPS*N*HD*2);
  P.Tb1   = (bf16*) alloc((size_t)N*HD*2);
  P.Tb2   = (bf16*) alloc((size_t)N*HD*2);
  P.zbf   = (bf16*) alloc((size_t)N*ZD*2);
  P.z_g   = (float*)alloc((size_t)N*HD*4);
  P.Gs1   = (bf16*) alloc((size_t)N*1024*2);
  P.Gsx   = (bf16*) alloc((size_t)N*768*2);
  P.Gms   = (bf16*) alloc((size_t)N*256*2);
  P.Gh2   = (bf16*) alloc((size_t)N*256*2);

  setup0_k<<<66,256,0,stream>>>(P);
  count_deg_k<<<1024,256,0,stream>>>(P);
  setup2_k<<<1060,256,0,stream>>>(P);
  for (int t = 0; t < T_STEPS; t++){
    g1_k<<<(t == 0) ? 2048 : 1024,256,0,stream>>>(P, t);   // t=0 carries edge scatter
    encagg_pms_k<<<640,256,0,stream>>>(P, t);
    encms_k<<<128,256,0,stream>>>(P, t);
    msaggpost_k<<<256,256,0,stream>>>(P, t);
    phiz_k<<<256,256,0,stream>>>(P, t);
    grux_dec_k<<<4864,256,0,stream>>>(P, t);
    zr_k<<<1024,256,0,stream>>>(P, t);
    hh_k<<<256,256,0,stream>>>(P, t);
    hagg_k<<<(t == T_STEPS-1) ? 513 : 512,256,0,stream>>>(P, t);
  }
}